// Round 11
// baseline (5729.209 us; speedup 1.0000x reference)
//
#include <hip/hip_runtime.h>
#include <cstdint>
#include <cstddef>

// Problem constants
#define V_ 10000
#define E_ 512
#define H_ 1024
#define L_ 2
#define B_ 64
#define T_ 128
#define G4_ (4 * H_)                 // 4096 gate width
#define SLOT (3 * 128 * 64 * 8)      // shorts per u timestep slot (3 planes)
#define PSTR 65536                   // shorts per u plane (128*64*8)

typedef __attribute__((ext_vector_type(8))) short bf16x8;
typedef __attribute__((ext_vector_type(4))) float f32x4;
typedef __attribute__((ext_vector_type(4))) unsigned int u32x4;

// ---------------------------------------------------------------------------
// bf16 split helpers (RNE; finite values only)
// ---------------------------------------------------------------------------
__device__ __forceinline__ unsigned short f2b(float x) {
    unsigned u = __float_as_uint(x);
    unsigned r = (u + 0x7FFFu + ((u >> 16) & 1u)) >> 16;
    return (unsigned short)r;
}
__device__ __forceinline__ float b2f(unsigned short h) {
    return __uint_as_float(((unsigned)h) << 16);
}
__device__ __forceinline__ void split3(float a, unsigned short& h, unsigned short& l, unsigned short& q) {
    h = f2b(a); float r = a - b2f(h);
    l = f2b(r); float r2 = r - b2f(l);
    q = f2b(r2);
}

// ---------------------------------------------------------------------------
// Embedding + concat: seq (T, B, E) rows m = t*64 + b
// ---------------------------------------------------------------------------
__global__ __launch_bounds__(128) void embed_kernel(
    const float* __restrict__ images, const int* __restrict__ captions,
    const float* __restrict__ table, float* __restrict__ seq)
{
    const int m = blockIdx.x;            // 0..8191
    const int t = m >> 6, b = m & 63;
    const float* src;
    if (t == 0) src = images + (size_t)b * E_;
    else        src = table + (size_t)captions[b * T_ + (t - 1)] * E_;
    float4 v = ((const float4*)src)[threadIdx.x];
    ((float4*)(seq + (size_t)m * E_))[threadIdx.x] = v;
}

// ---------------------------------------------------------------------------
// f32 -> 3 bf16 plane split (plane stride = n elements)
// ---------------------------------------------------------------------------
__global__ __launch_bounds__(256) void split_planes(
    const float* __restrict__ in, unsigned short* __restrict__ pl, size_t n)
{
    size_t i = ((size_t)blockIdx.x * 256 + threadIdx.x) * 4;
    if (i >= n) return;
    float4 v = *(const float4*)&in[i];
    unsigned short h[4], l[4], q[4];
    split3(v.x, h[0], l[0], q[0]); split3(v.y, h[1], l[1], q[1]);
    split3(v.z, h[2], l[2], q[2]); split3(v.w, h[3], l[3], q[3]);
    ushort4 hv = {h[0], h[1], h[2], h[3]};
    ushort4 lv = {l[0], l[1], l[2], l[3]};
    ushort4 qv = {q[0], q[1], q[2], q[3]};
    *(ushort4*)&pl[i]         = hv;
    *(ushort4*)&pl[n + i]     = lv;
    *(ushort4*)&pl[2 * n + i] = qv;
}

// ---------------------------------------------------------------------------
// Split-bf16x6 MFMA GEMM, in-kernel split of both operands.
// Used for weight products (K,N f32 B). C = A(M,K) @ B(K,N), f32 out.
// ---------------------------------------------------------------------------
template<bool BNK>
__global__ __launch_bounds__(256) void mfma_gemm(
    const float* __restrict__ A, const float* __restrict__ Bm, float* __restrict__ C,
    int M, int N, int K,
    const float* __restrict__ bias1, const float* __restrict__ bias2)
{
    __shared__ unsigned short As[3][128][40];
    __shared__ unsigned short Bs[3][128][40];
    const int bm = blockIdx.y * 128, bn = blockIdx.x * 128;
    const int tid = threadIdx.x;
    const int lane = tid & 63, wid = tid >> 6;
    const int wm = wid >> 1, wn = wid & 1;
    const int lr = lane & 15, lk = (lane >> 4) * 8;

    f32x4 acc[4][4] = {};

    for (int k0 = 0; k0 < K; k0 += 32) {
        #pragma unroll
        for (int p = 0; p < 4; ++p) {
            int flat = p * 256 + tid;
            int c4 = flat & 7, r = flat >> 3;
            float4 v = *(const float4*)&A[(size_t)(bm + r) * K + k0 + c4 * 4];
            unsigned short h[4], l[4], q[4];
            split3(v.x, h[0], l[0], q[0]); split3(v.y, h[1], l[1], q[1]);
            split3(v.z, h[2], l[2], q[2]); split3(v.w, h[3], l[3], q[3]);
            unsigned* dh = (unsigned*)&As[0][r][c4 * 4];
            dh[0] = h[0] | ((unsigned)h[1] << 16); dh[1] = h[2] | ((unsigned)h[3] << 16);
            unsigned* dl = (unsigned*)&As[1][r][c4 * 4];
            dl[0] = l[0] | ((unsigned)l[1] << 16); dl[1] = l[2] | ((unsigned)l[3] << 16);
            unsigned* dq = (unsigned*)&As[2][r][c4 * 4];
            dq[0] = q[0] | ((unsigned)q[1] << 16); dq[1] = q[2] | ((unsigned)q[3] << 16);
        }
        if (BNK) {
            #pragma unroll
            for (int p = 0; p < 4; ++p) {
                int flat = p * 256 + tid;
                int c4 = flat & 7, r = flat >> 3;
                float4 v = *(const float4*)&Bm[(size_t)(bn + r) * K + k0 + c4 * 4];
                unsigned short h[4], l[4], q[4];
                split3(v.x, h[0], l[0], q[0]); split3(v.y, h[1], l[1], q[1]);
                split3(v.z, h[2], l[2], q[2]); split3(v.w, h[3], l[3], q[3]);
                unsigned* dh = (unsigned*)&Bs[0][r][c4 * 4];
                dh[0] = h[0] | ((unsigned)h[1] << 16); dh[1] = h[2] | ((unsigned)h[3] << 16);
                unsigned* dl = (unsigned*)&Bs[1][r][c4 * 4];
                dl[0] = l[0] | ((unsigned)l[1] << 16); dl[1] = l[2] | ((unsigned)l[3] << 16);
                unsigned* dq = (unsigned*)&Bs[2][r][c4 * 4];
                dq[0] = q[0] | ((unsigned)q[1] << 16); dq[1] = q[2] | ((unsigned)q[3] << 16);
            }
        } else {
            #pragma unroll
            for (int p = 0; p < 4; ++p) {
                int flat = p * 256 + tid;
                int n4 = flat & 31, kr = flat >> 5;
                float4 v = *(const float4*)&Bm[(size_t)(k0 + kr) * N + bn + n4 * 4];
                float vv[4] = {v.x, v.y, v.z, v.w};
                #pragma unroll
                for (int jj = 0; jj < 4; ++jj) {
                    unsigned short h, l, q; split3(vv[jj], h, l, q);
                    Bs[0][n4 * 4 + jj][kr] = h;
                    Bs[1][n4 * 4 + jj][kr] = l;
                    Bs[2][n4 * 4 + jj][kr] = q;
                }
            }
        }
        __syncthreads();

        bf16x8 af[3][4], bf[3][4];
        #pragma unroll
        for (int pl = 0; pl < 3; ++pl)
            #pragma unroll
            for (int m = 0; m < 4; ++m) {
                af[pl][m] = *(const bf16x8*)&As[pl][wm * 64 + m * 16 + lr][lk];
                bf[pl][m] = *(const bf16x8*)&Bs[pl][wn * 64 + m * 16 + lr][lk];
            }
        #pragma unroll
        for (int m = 0; m < 4; ++m)
            #pragma unroll
            for (int n = 0; n < 4; ++n) {
                acc[m][n] = __builtin_amdgcn_mfma_f32_16x16x32_bf16(af[0][m], bf[0][n], acc[m][n], 0, 0, 0);
                acc[m][n] = __builtin_amdgcn_mfma_f32_16x16x32_bf16(af[0][m], bf[1][n], acc[m][n], 0, 0, 0);
                acc[m][n] = __builtin_amdgcn_mfma_f32_16x16x32_bf16(af[1][m], bf[0][n], acc[m][n], 0, 0, 0);
                acc[m][n] = __builtin_amdgcn_mfma_f32_16x16x32_bf16(af[1][m], bf[1][n], acc[m][n], 0, 0, 0);
                acc[m][n] = __builtin_amdgcn_mfma_f32_16x16x32_bf16(af[0][m], bf[2][n], acc[m][n], 0, 0, 0);
                acc[m][n] = __builtin_amdgcn_mfma_f32_16x16x32_bf16(af[2][m], bf[0][n], acc[m][n], 0, 0, 0);
            }
        __syncthreads();
    }

    float bv[4];
    #pragma unroll
    for (int n = 0; n < 4; ++n) {
        int col = bn + wn * 64 + n * 16 + lr;
        float x = 0.f;
        if (bias1) x += bias1[col];
        if (bias2) x += bias2[col];
        bv[n] = x;
    }
    #pragma unroll
    for (int m = 0; m < 4; ++m) {
        int rbase = bm + wm * 64 + m * 16 + (lane >> 4) * 4;
        #pragma unroll
        for (int n = 0; n < 4; ++n) {
            int col = bn + wn * 64 + n * 16 + lr;
            #pragma unroll
            for (int r = 0; r < 4; ++r)
                C[(size_t)(rbase + r) * N + col] = acc[m][n][r] + bv[n];
        }
    }
}

// ---------------------------------------------------------------------------
// X GEMM (layer 0 only): Xr[t][col][b] = seq(8192,512) @ W_ih0^T + b0
// ---------------------------------------------------------------------------
__global__ __launch_bounds__(256) void xgemm_kernel(
    const float* __restrict__ A, const unsigned short* __restrict__ Bpl,
    const float* __restrict__ bias1, const float* __restrict__ bias2,
    float* __restrict__ Xr)
{
    __shared__ unsigned short As[3][128][40];
    __shared__ unsigned short Bs[3][128][40];
    const int bm = blockIdx.y * 128, bn = blockIdx.x * 128;
    const int tid = threadIdx.x;
    const int lane = tid & 63, wid = tid >> 6;
    const int wm = wid >> 1, wn = wid & 1;
    const int lr = lane & 15, lg = lane >> 4, lk = lg * 8;

    f32x4 acc[4][4] = {};

    for (int k0 = 0; k0 < E_; k0 += 32) {
        #pragma unroll
        for (int p = 0; p < 4; ++p) {
            int flat = p * 256 + tid;
            int c4 = flat & 7, r = flat >> 3;
            float4 v = *(const float4*)&A[(size_t)(bm + r) * E_ + k0 + c4 * 4];
            unsigned short h[4], l[4], q[4];
            split3(v.x, h[0], l[0], q[0]); split3(v.y, h[1], l[1], q[1]);
            split3(v.z, h[2], l[2], q[2]); split3(v.w, h[3], l[3], q[3]);
            unsigned* dh = (unsigned*)&As[0][r][c4 * 4];
            dh[0] = h[0] | ((unsigned)h[1] << 16); dh[1] = h[2] | ((unsigned)h[3] << 16);
            unsigned* dl = (unsigned*)&As[1][r][c4 * 4];
            dl[0] = l[0] | ((unsigned)l[1] << 16); dl[1] = l[2] | ((unsigned)l[3] << 16);
            unsigned* dq = (unsigned*)&As[2][r][c4 * 4];
            dq[0] = q[0] | ((unsigned)q[1] << 16); dq[1] = q[2] | ((unsigned)q[3] << 16);
        }
        #pragma unroll
        for (int p6 = 0; p6 < 6; ++p6) {
            int f = p6 * 256 + tid;
            int pl = f >> 9, rem = f & 511;
            int r = rem >> 2, g4 = rem & 3;
            const unsigned short* src = Bpl + (size_t)pl * (G4_ * E_) + (size_t)(bn + r) * E_ + k0 + g4 * 8;
            *(uint4*)&Bs[pl][r][g4 * 8] = *(const uint4*)src;
        }
        __syncthreads();

        bf16x8 af[3][4], bf[3][4];
        #pragma unroll
        for (int pl = 0; pl < 3; ++pl)
            #pragma unroll
            for (int m = 0; m < 4; ++m) {
                af[pl][m] = *(const bf16x8*)&As[pl][wm * 64 + m * 16 + lr][lk];
                bf[pl][m] = *(const bf16x8*)&Bs[pl][wn * 64 + m * 16 + lr][lk];
            }
        #pragma unroll
        for (int m = 0; m < 4; ++m)
            #pragma unroll
            for (int n = 0; n < 4; ++n) {
                acc[m][n] = __builtin_amdgcn_mfma_f32_16x16x32_bf16(af[0][m], bf[0][n], acc[m][n], 0, 0, 0);
                acc[m][n] = __builtin_amdgcn_mfma_f32_16x16x32_bf16(af[0][m], bf[1][n], acc[m][n], 0, 0, 0);
                acc[m][n] = __builtin_amdgcn_mfma_f32_16x16x32_bf16(af[1][m], bf[0][n], acc[m][n], 0, 0, 0);
                acc[m][n] = __builtin_amdgcn_mfma_f32_16x16x32_bf16(af[1][m], bf[1][n], acc[m][n], 0, 0, 0);
                acc[m][n] = __builtin_amdgcn_mfma_f32_16x16x32_bf16(af[0][m], bf[2][n], acc[m][n], 0, 0, 0);
                acc[m][n] = __builtin_amdgcn_mfma_f32_16x16x32_bf16(af[2][m], bf[0][n], acc[m][n], 0, 0, 0);
            }
        __syncthreads();
    }

    #pragma unroll
    for (int n = 0; n < 4; ++n) {
        int col = bn + wn * 64 + n * 16 + lr;
        float bv = bias1[col] + bias2[col];
        #pragma unroll
        for (int m = 0; m < 4; ++m) {
            int rbase = bm + wm * 64 + m * 16 + lg * 4;
            #pragma unroll
            for (int r = 0; r < 4; ++r) {
                int row = rbase + r;
                Xr[((size_t)(row >> 6) * G4_ + col) * 64 + (row & 63)] = acc[m][n][r] + bv;
            }
        }
    }
}

// ---------------------------------------------------------------------------
// Fused 2-layer pipelined LSTM recurrence: 256 blocks x 512 threads, 129 ticks.
// Blocks 0-127: layer 0 (R10-exact step; u0 kept in a 2-slot ring).
// Blocks 128-255: layer 1, lagged 1 tick: gates1 = u0(t)@Wx1^T + u1(t-1)@
// Whhr1^T + b1 (Wx1 = W_ih1@W_hr0 precomputed). 8 waves = 2 matrices x 4
// batch-quadrants; hi planes of both matrices in LDS, lo+q streamed.
// Barrier/coherence: R10-proven (sc0sc1 write-through u stores + vmcnt drain;
// relaxed direct-poll barrier, 32 counters x 8 blocks, monotone targets).
// ---------------------------------------------------------------------------
__global__ __launch_bounds__(512, 1) void persistent_lstm(
    const float* __restrict__ Xr,               // [128][4096][64]
    const unsigned short* __restrict__ Wpl0,    // [3][4096*1024] layer0 Whhr
    const unsigned short* __restrict__ WplX,    // [3][4096*1024] Wx1
    const unsigned short* __restrict__ Wpl1,    // [3][4096*1024] layer1 Whhr
    unsigned short* __restrict__ u0r,           // [2][SLOT] ring
    unsigned short* __restrict__ u1ps,          // [129][SLOT]
    const float* __restrict__ bih1,
    const float* __restrict__ bhh1,
    unsigned int* bar)                          // 32 counters, 64B apart
{
    extern __shared__ unsigned short smem[];
    unsigned short* Wlds = smem;                // 131072 B
    unsigned short* u_sm = smem + 65536;        // 3072 B
    float* psum = (float*)(smem + 67072);       // 8192 B

    const int tid = threadIdx.x;
    const int j = blockIdx.x;                   // 0..255
    const int wid = tid >> 6, lane = tid & 63;
    const int grp = wid >> 2, bq = wid & 3;     // L0: k-half; L1: matrix
    const int lr = lane & 15, lg = lane >> 4;
    const bool isL0 = (j < 128);
    const int jj = isL0 ? j : (j - 128);
    const int b = bq * 16 + lr;
    const int uoff = b * 8;
    const int swzb = lr & 7;
    const int gr0 = (lr & 3) * 1024 + jj * 8 + (lr >> 2);
    const int gr1 = gr0 + 4;

    float c0 = 0.f, c1 = 0.f;
    float b1v0[4], b1v1[4];

    if (isL0) {
        // stage hi/lo planes of Whhr0's 32 gate-rows (R10-exact)
        for (int it = 0; it < 16; ++it) {
            int f = it * 512 + tid;
            int p = f >> 12;
            int rem = f & 4095;
            int h2 = rem >> 11;
            int rem2 = rem & 2047;
            int n = rem2 >> 7;
            int g16 = rem2 & 127;
            int gr = (n & 3) * 1024 + jj * 8 + h2 * 4 + (n >> 2);
            const unsigned short* src = Wpl0 + (size_t)p * (G4_ * H_) + (size_t)gr * H_ + g16 * 8;
            *(uint4*)&Wlds[(size_t)((p * 2 + h2) * 16 + n) * 1024 + (g16 ^ (n & 7)) * 8] = *(const uint4*)src;
        }
    } else {
        // stage hi planes of BOTH matrices (Wx1, Whhr1): [mat][h2][16][1024]
        for (int it = 0; it < 16; ++it) {
            int f = it * 512 + tid;
            int m = f >> 12;
            int rem = f & 4095;
            int h2 = rem >> 11;
            int rem2 = rem & 2047;
            int n = rem2 >> 7;
            int g16 = rem2 & 127;
            int gr = (n & 3) * 1024 + jj * 8 + h2 * 4 + (n >> 2);
            const unsigned short* base = (m == 0) ? WplX : Wpl1;
            const unsigned short* src = base + (size_t)gr * H_ + g16 * 8;   // plane 0 = hi
            *(uint4*)&Wlds[(size_t)((m * 2 + h2) * 16 + n) * 1024 + (g16 ^ (n & 7)) * 8] = *(const uint4*)src;
        }
        #pragma unroll
        for (int g = 0; g < 4; ++g) {
            int idx = g * 1024 + jj * 8 + lg;
            b1v0[g] = bih1[idx] + bhh1[idx];
            b1v1[g] = bih1[idx + 4] + bhh1[idx + 4];
        }
    }
    __syncthreads();

    const unsigned short* wq0 = Wpl0 + (size_t)2 * (G4_ * H_) + (size_t)gr0 * H_;
    const unsigned short* wq1 = Wpl0 + (size_t)2 * (G4_ * H_) + (size_t)gr1 * H_;
    // L1 streamed rows of this wave's matrix (lo=plane1, q=plane2)
    const unsigned short* mbase = (grp == 0) ? WplX : Wpl1;
    const unsigned short* ml0 = mbase + (size_t)1 * (G4_ * H_) + (size_t)gr0 * H_;
    const unsigned short* ml1 = mbase + (size_t)1 * (G4_ * H_) + (size_t)gr1 * H_;
    const unsigned short* mq0 = mbase + (size_t)2 * (G4_ * H_) + (size_t)gr0 * H_;
    const unsigned short* mq1 = mbase + (size_t)2 * (G4_ * H_) + (size_t)gr1 * H_;

    for (int tau = 0; tau <= T_; ++tau) {
        if (isL0) {
            if (tau < T_) {
                const int t = tau;
                const unsigned short* ut = u0r + (size_t)(t & 1) * SLOT;
                float xg0[4], xg1[4];
                if (grp == 0) {
                    #pragma unroll
                    for (int g = 0; g < 4; ++g) {
                        xg0[g] = Xr[((size_t)t * G4_ + g * 1024 + jj * 8 + lg) * 64 + b];
                        xg1[g] = Xr[((size_t)t * G4_ + g * 1024 + jj * 8 + 4 + lg) * 64 + b];
                    }
                }
                f32x4 a0 = {0.f,0.f,0.f,0.f}, p0 = {0.f,0.f,0.f,0.f};
                f32x4 a1 = {0.f,0.f,0.f,0.f}, p1 = {0.f,0.f,0.f,0.f};
                const int kbase = grp * 64;
                #pragma unroll 8
                for (int ks = 0; ks < 16; ++ks) {
                    int g16 = kbase + ks * 4 + lg;
                    int swz = (g16 ^ swzb) * 8;
                    bf16x8 uh = *(const bf16x8*)&ut[(size_t)g16 * 512 + uoff];
                    bf16x8 ul = *(const bf16x8*)&ut[PSTR + (size_t)g16 * 512 + uoff];
                    bf16x8 uq = *(const bf16x8*)&ut[2 * PSTR + (size_t)g16 * 512 + uoff];
                    bf16x8 wh0 = *(const bf16x8*)&Wlds[(size_t)(0 * 16 + lr) * 1024 + swz];
                    bf16x8 wh1 = *(const bf16x8*)&Wlds[(size_t)(1 * 16 + lr) * 1024 + swz];
                    bf16x8 wl0 = *(const bf16x8*)&Wlds[(size_t)(2 * 16 + lr) * 1024 + swz];
                    bf16x8 wl1 = *(const bf16x8*)&Wlds[(size_t)(3 * 16 + lr) * 1024 + swz];
                    bf16x8 wq0v = *(const bf16x8*)&wq0[g16 * 8];
                    bf16x8 wq1v = *(const bf16x8*)&wq1[g16 * 8];
                    a0 = __builtin_amdgcn_mfma_f32_16x16x32_bf16(wh0, uh, a0, 0, 0, 0);
                    a0 = __builtin_amdgcn_mfma_f32_16x16x32_bf16(wh0, ul, a0, 0, 0, 0);
                    a0 = __builtin_amdgcn_mfma_f32_16x16x32_bf16(wl0, uh, a0, 0, 0, 0);
                    p0 = __builtin_amdgcn_mfma_f32_16x16x32_bf16(wl0, ul, p0, 0, 0, 0);
                    p0 = __builtin_amdgcn_mfma_f32_16x16x32_bf16(wh0, uq, p0, 0, 0, 0);
                    p0 = __builtin_amdgcn_mfma_f32_16x16x32_bf16(wq0v, uh, p0, 0, 0, 0);
                    a1 = __builtin_amdgcn_mfma_f32_16x16x32_bf16(wh1, uh, a1, 0, 0, 0);
                    a1 = __builtin_amdgcn_mfma_f32_16x16x32_bf16(wh1, ul, a1, 0, 0, 0);
                    a1 = __builtin_amdgcn_mfma_f32_16x16x32_bf16(wl1, uh, a1, 0, 0, 0);
                    p1 = __builtin_amdgcn_mfma_f32_16x16x32_bf16(wl1, ul, p1, 0, 0, 0);
                    p1 = __builtin_amdgcn_mfma_f32_16x16x32_bf16(wh1, uq, p1, 0, 0, 0);
                    p1 = __builtin_amdgcn_mfma_f32_16x16x32_bf16(wq1v, uh, p1, 0, 0, 0);
                }
                if (grp == 1) {
                    float* pp = &psum[(size_t)(bq * 64 + lane) * 8];
                    *(f32x4*)&pp[0] = a0 + p0;
                    *(f32x4*)&pp[4] = a1 + p1;
                }
                __syncthreads();
                if (grp == 0) {
                    const float* pp = &psum[(size_t)(bq * 64 + lane) * 8];
                    f32x4 s0o = *(const f32x4*)&pp[0];
                    f32x4 s1o = *(const f32x4*)&pp[4];
                    {
                        float gi = a0[0]+p0[0]+s0o[0]+xg0[0];
                        float gf = a0[1]+p0[1]+s0o[1]+xg0[1];
                        float gv = a0[2]+p0[2]+s0o[2]+xg0[2];
                        float go = a0[3]+p0[3]+s0o[3]+xg0[3];
                        float si = 1.f/(1.f+__expf(-gi));
                        float sf = 1.f/(1.f+__expf(-gf));
                        float so = 1.f/(1.f+__expf(-go));
                        c0 = sf*c0 + si*tanhf(gv);
                        float ho = so*tanhf(c0);
                        unsigned short sh, sl, sq; split3(ho, sh, sl, sq);
                        u_sm[(0*64+b)*8+lg] = sh; u_sm[(1*64+b)*8+lg] = sl; u_sm[(2*64+b)*8+lg] = sq;
                    }
                    {
                        float gi = a1[0]+p1[0]+s1o[0]+xg1[0];
                        float gf = a1[1]+p1[1]+s1o[1]+xg1[1];
                        float gv = a1[2]+p1[2]+s1o[2]+xg1[2];
                        float go = a1[3]+p1[3]+s1o[3]+xg1[3];
                        float si = 1.f/(1.f+__expf(-gi));
                        float sf = 1.f/(1.f+__expf(-gf));
                        float so = 1.f/(1.f+__expf(-go));
                        c1 = sf*c1 + si*tanhf(gv);
                        float ho = so*tanhf(c1);
                        unsigned short sh, sl, sq; split3(ho, sh, sl, sq);
                        u_sm[(0*64+b)*8+4+lg] = sh; u_sm[(1*64+b)*8+4+lg] = sl; u_sm[(2*64+b)*8+4+lg] = sq;
                    }
                }
                __syncthreads();
                if (tid < 192) {
                    int pl = tid >> 6, bb = tid & 63;
                    u32x4 v = *(const u32x4*)&u_sm[(pl * 64 + bb) * 8];
                    unsigned short* dst = u0r + (size_t)((t + 1) & 1) * SLOT
                                        + (size_t)pl * PSTR + (size_t)(jj * 64 + bb) * 8;
                    asm volatile("global_store_dwordx4 %0, %1, off sc0 sc1"
                                 :: "v"(dst), "v"(v) : "memory");
                }
            }
        } else {
            if (tau >= 1) {
                const int t = tau;
                const unsigned short* u0b = u0r + (size_t)(t & 1) * SLOT;      // u0(t)
                const unsigned short* u1b = u1ps + (size_t)(t - 1) * SLOT;     // u1(t-1)
                const unsigned short* ub = (grp == 0) ? u0b : u1b;
                f32x4 a0 = {0.f,0.f,0.f,0.f}, p0 = {0.f,0.f,0.f,0.f};
                f32x4 a1 = {0.f,0.f,0.f,0.f}, p1 = {0.f,0.f,0.f,0.f};
                const int lbase = grp * 32;   // LDS row base for this matrix
                #pragma unroll 8
                for (int ks = 0; ks < 32; ++ks) {
                    int g16 = ks * 4 + lg;
                    int swz = (g16 ^ swzb) * 8;
                    bf16x8 uh = *(const bf16x8*)&ub[(size_t)g16 * 512 + uoff];
                    bf16x8 ul = *(const bf16x8*)&ub[PSTR + (size_t)g16 * 512 + uoff];
                    bf16x8 uq = *(const bf16x8*)&ub[2 * PSTR + (size_t)g16 * 512 + uoff];
                    bf16x8 wh0 = *(const bf16x8*)&Wlds[(size_t)(lbase + lr) * 1024 + swz];
                    bf16x8 wh1 = *(const bf16x8*)&Wlds[(size_t)(lbase + 16 + lr) * 1024 + swz];
                    bf16x8 wl0v = *(const bf16x8*)&ml0[g16 * 8];
                    bf16x8 wl1v = *(const bf16x8*)&ml1[g16 * 8];
                    bf16x8 wq0v = *(const bf16x8*)&mq0[g16 * 8];
                    bf16x8 wq1v = *(const bf16x8*)&mq1[g16 * 8];
                    a0 = __builtin_amdgcn_mfma_f32_16x16x32_bf16(wh0, uh, a0, 0, 0, 0);
                    a0 = __builtin_amdgcn_mfma_f32_16x16x32_bf16(wh0, ul, a0, 0, 0, 0);
                    a0 = __builtin_amdgcn_mfma_f32_16x16x32_bf16(wl0v, uh, a0, 0, 0, 0);
                    p0 = __builtin_amdgcn_mfma_f32_16x16x32_bf16(wl0v, ul, p0, 0, 0, 0);
                    p0 = __builtin_amdgcn_mfma_f32_16x16x32_bf16(wh0, uq, p0, 0, 0, 0);
                    p0 = __builtin_amdgcn_mfma_f32_16x16x32_bf16(wq0v, uh, p0, 0, 0, 0);
                    a1 = __builtin_amdgcn_mfma_f32_16x16x32_bf16(wh1, uh, a1, 0, 0, 0);
                    a1 = __builtin_amdgcn_mfma_f32_16x16x32_bf16(wh1, ul, a1, 0, 0, 0);
                    a1 = __builtin_amdgcn_mfma_f32_16x16x32_bf16(wl1v, uh, a1, 0, 0, 0);
                    p1 = __builtin_amdgcn_mfma_f32_16x16x32_bf16(wl1v, ul, p1, 0, 0, 0);
                    p1 = __builtin_amdgcn_mfma_f32_16x16x32_bf16(wh1, uq, p1, 0, 0, 0);
                    p1 = __builtin_amdgcn_mfma_f32_16x16x32_bf16(wq1v, uh, p1, 0, 0, 0);
                }
                if (grp == 1) {
                    float* pp = &psum[(size_t)(bq * 64 + lane) * 8];
                    *(f32x4*)&pp[0] = a0 + p0;
                    *(f32x4*)&pp[4] = a1 + p1;
                }
                __syncthreads();
                if (grp == 0) {
                    const float* pp = &psum[(size_t)(bq * 64 + lane) * 8];
                    f32x4 s0o = *(const f32x4*)&pp[0];
                    f32x4 s1o = *(const f32x4*)&pp[4];
                    {
                        float gi = a0[0]+p0[0]+s0o[0]+b1v0[0];
                        float gf = a0[1]+p0[1]+s0o[1]+b1v0[1];
                        float gv = a0[2]+p0[2]+s0o[2]+b1v0[2];
                        float go = a0[3]+p0[3]+s0o[3]+b1v0[3];
                        float si = 1.f/(1.f+__expf(-gi));
                        float sf = 1.f/(1.f+__expf(-gf));
                        float so = 1.f/(1.f+__expf(-go));
                        c0 = sf*c0 + si*tanhf(gv);
                        float ho = so*tanhf(c0);
                        unsigned short sh, sl, sq; split3(ho, sh, sl, sq);
                        u_sm[(0*64+b)*8+lg] = sh; u_sm[(1*64+b)*8+lg] = sl; u_sm[(2*64+b)*8+lg] = sq;
                    }
                    {
                        float gi = a1[0]+p1[0]+s1o[0]+b1v1[0];
                        float gf = a1[1]+p1[1]+s1o[1]+b1v1[1];
                        float gv = a1[2]+p1[2]+s1o[2]+b1v1[2];
                        float go = a1[3]+p1[3]+s1o[3]+b1v1[3];
                        float si = 1.f/(1.f+__expf(-gi));
                        float sf = 1.f/(1.f+__expf(-gf));
                        float so = 1.f/(1.f+__expf(-go));
                        c1 = sf*c1 + si*tanhf(gv);
                        float ho = so*tanhf(c1);
                        unsigned short sh, sl, sq; split3(ho, sh, sl, sq);
                        u_sm[(0*64+b)*8+4+lg] = sh; u_sm[(1*64+b)*8+4+lg] = sl; u_sm[(2*64+b)*8+4+lg] = sq;
                    }
                }
                __syncthreads();
                if (tid < 192) {
                    int pl = tid >> 6, bb = tid & 63;
                    u32x4 v = *(const u32x4*)&u_sm[(pl * 64 + bb) * 8];
                    unsigned short* dst = u1ps + (size_t)t * SLOT
                                        + (size_t)pl * PSTR + (size_t)(jj * 64 + bb) * 8;
                    asm volatile("global_store_dwordx4 %0, %1, off sc0 sc1"
                                 :: "v"(dst), "v"(v) : "memory");
                }
            }
        }

        if (tau < T_) {
            asm volatile("s_waitcnt vmcnt(0)" ::: "memory");
            __syncthreads();
            if (tid == 0)
                __hip_atomic_fetch_add(&bar[(j & 31) * 16], 1u,
                                       __ATOMIC_RELAXED, __HIP_MEMORY_SCOPE_AGENT);
            if (tid < 32) {
                const unsigned tgt = (unsigned)(tau + 1) * 8u;
                while (__hip_atomic_load(&bar[tid * 16],
                                         __ATOMIC_RELAXED, __HIP_MEMORY_SCOPE_AGENT) < tgt) {}
            }
            __syncthreads();
        }
    }
}

// ---------------------------------------------------------------------------
// Projection GEMM: logits(8192,512) = U1(8192,1024) @ W_hr1^T
// ---------------------------------------------------------------------------
__global__ __launch_bounds__(256) void proj_gemm(
    const unsigned short* __restrict__ u_ps,   // [129][SLOT]
    const float* __restrict__ Whr,             // (512,1024) f32 (N,K)
    float* __restrict__ C)                     // (8192,512)
{
    __shared__ unsigned short Bs[3][128][40];
    const int bn = blockIdx.x * 128;
    const int bm = blockIdx.y * 128;
    const int tid = threadIdx.x;
    const int lane = tid & 63, wid = tid >> 6;
    const int wm = wid >> 1, wn = wid & 1;
    const int lr = lane & 15, lg = lane >> 4, lk = lg * 8;

    f32x4 acc[4][4] = {};
    const int t = (bm >> 6) + wm;
    const unsigned short* ut = u_ps + (size_t)(t + 1) * SLOT;

    for (int k0 = 0; k0 < H_; k0 += 32) {
        #pragma unroll
        for (int p = 0; p < 4; ++p) {
            int flat = p * 256 + tid;
            int c4 = flat & 7, r = flat >> 3;
            float4 v = *(const float4*)&Whr[(size_t)(bn + r) * H_ + k0 + c4 * 4];
            unsigned short h[4], l[4], q[4];
            split3(v.x, h[0], l[0], q[0]); split3(v.y, h[1], l[1], q[1]);
            split3(v.z, h[2], l[2], q[2]); split3(v.w, h[3], l[3], q[3]);
            unsigned* dh = (unsigned*)&Bs[0][r][c4 * 4];
            dh[0] = h[0] | ((unsigned)h[1] << 16); dh[1] = h[2] | ((unsigned)h[3] << 16);
            unsigned* dl = (unsigned*)&Bs[1][r][c4 * 4];
            dl[0] = l[0] | ((unsigned)l[1] << 16); dl[1] = l[2] | ((unsigned)l[3] << 16);
            unsigned* dq = (unsigned*)&Bs[2][r][c4 * 4];
            dq[0] = q[0] | ((unsigned)q[1] << 16); dq[1] = q[2] | ((unsigned)q[3] << 16);
        }
        __syncthreads();

        int ks = k0 >> 5;
        bf16x8 af[3][4], bf[3][4];
        #pragma unroll
        for (int pl = 0; pl < 3; ++pl)
            #pragma unroll
            for (int m = 0; m < 4; ++m) {
                af[pl][m] = *(const bf16x8*)&ut[(size_t)pl * PSTR + (size_t)((ks * 4 + lg) * 64 + m * 16 + lr) * 8];
                bf[pl][m] = *(const bf16x8*)&Bs[pl][wn * 64 + m * 16 + lr][lk];
            }
        #pragma unroll
        for (int m = 0; m < 4; ++m)
            #pragma unroll
            for (int n = 0; n < 4; ++n) {
                acc[m][n] = __builtin_amdgcn_mfma_f32_16x16x32_bf16(af[0][m], bf[0][n], acc[m][n], 0, 0, 0);
                acc[m][n] = __builtin_amdgcn_mfma_f32_16x16x32_bf16(af[0][m], bf[1][n], acc[m][n], 0, 0, 0);
                acc[m][n] = __builtin_amdgcn_mfma_f32_16x16x32_bf16(af[1][m], bf[0][n], acc[m][n], 0, 0, 0);
                acc[m][n] = __builtin_amdgcn_mfma_f32_16x16x32_bf16(af[1][m], bf[1][n], acc[m][n], 0, 0, 0);
                acc[m][n] = __builtin_amdgcn_mfma_f32_16x16x32_bf16(af[0][m], bf[2][n], acc[m][n], 0, 0, 0);
                acc[m][n] = __builtin_amdgcn_mfma_f32_16x16x32_bf16(af[2][m], bf[0][n], acc[m][n], 0, 0, 0);
            }
        __syncthreads();
    }

    #pragma unroll
    for (int m = 0; m < 4; ++m) {
        int rbase = bm + wm * 64 + m * 16 + lg * 4;
        #pragma unroll
        for (int n = 0; n < 4; ++n) {
            int col = bn + wn * 64 + n * 16 + lr;
            #pragma unroll
            for (int r = 0; r < 4; ++r)
                C[(size_t)(rbase + r) * E_ + col] = acc[m][n][r];
        }
    }
}

// ---------------------------------------------------------------------------
// Row softmax over E=512; input rows m = t*64+b, output row (b, t).
// ---------------------------------------------------------------------------
__global__ __launch_bounds__(256) void softmax_kernel(
    const float* __restrict__ LOG, float* __restrict__ out)
{
    const int lane = threadIdx.x & 63;
    const int r = blockIdx.x * 4 + (threadIdx.x >> 6);
    const float* src = LOG + (size_t)r * E_;
    float v[8];
    *(float4*)&v[0] = ((const float4*)src)[lane * 2];
    *(float4*)&v[4] = ((const float4*)src)[lane * 2 + 1];

    float m = v[0];
    #pragma unroll
    for (int i = 1; i < 8; ++i) m = fmaxf(m, v[i]);
    #pragma unroll
    for (int off = 32; off > 0; off >>= 1) m = fmaxf(m, __shfl_xor(m, off, 64));

    float s = 0.f;
    #pragma unroll
    for (int i = 0; i < 8; ++i) { v[i] = expf(v[i] - m); s += v[i]; }
    #pragma unroll
    for (int off = 32; off > 0; off >>= 1) s += __shfl_xor(s, off, 64);
    const float inv = 1.f / s;

    const int t = r >> 6, b = r & 63;
    float* dst = out + ((size_t)b * T_ + t) * E_;
    #pragma unroll
    for (int i = 0; i < 8; ++i) v[i] *= inv;
    ((float4*)dst)[lane * 2]     = *(float4*)&v[0];
    ((float4*)dst)[lane * 2 + 1] = *(float4*)&v[4];
}

// ---------------------------------------------------------------------------
extern "C" void kernel_launch(void* const* d_in, const int* in_sizes, int n_in,
                              void* d_out, int out_size, void* d_ws, size_t ws_size,
                              hipStream_t stream)
{
    const float* images   = (const float*)d_in[0];
    const int*   captions = (const int*)  d_in[1];
    const float* table    = (const float*)d_in[2];
    const float* W_ih     = (const float*)d_in[3];
    const float* W_hh     = (const float*)d_in[4];
    const float* W_hr     = (const float*)d_in[5];
    const float* b_ih     = (const float*)d_in[6];
    const float* b_hh     = (const float*)d_in[7];
    float* out = (float*)d_out;

    // Workspace layout (byte offsets)
    char* base = (char*)d_ws;
    float*          Xr    = (float*)base;                            // 134,217,728
    unsigned int*   bar   = (unsigned int*)(base + 134217728);       //       4,096
    unsigned short* u0r   = (unsigned short*)(base + 134221824);     //     786,432 (2 slots)
    unsigned short* u1ps  = (unsigned short*)(base + 135008256);     //  50,724,864 (129 slots)
    unsigned short* Wpl0  = (unsigned short*)(base + 185733120);     //  25,165,824
    unsigned short* Wpl1  = (unsigned short*)(base + 210898944);     //  25,165,824
    unsigned short* WplX  = (unsigned short*)(base + 236064768);     //  25,165,824
    // sequentially-dead aliases inside u1ps (overwritten later by coop kernel)
    float* WF32 = (float*)((char*)u1ps + 393216);                    // 16.8MB scratch
    float* seq  = (float*)((char*)u1ps + 17170432);                  // 16.8MB
    float* logits = Xr;

    const int SMEM_BYTES = 131072 + 3072 + 8192;
    (void)hipFuncSetAttribute((const void*)persistent_lstm,
                              hipFuncAttributeMaxDynamicSharedMemorySize, SMEM_BYTES);

    const float* wih0 = W_ih;
    const float* wih1 = W_ih + (size_t)G4_ * E_;
    const float* whh0 = W_hh;
    const float* whh1 = W_hh + (size_t)G4_ * E_;
    const float* whr0 = W_hr;
    const float* whr1 = W_hr + (size_t)E_ * H_;

    embed_kernel<<<T_ * B_, 128, 0, stream>>>(images, captions, table, seq);

    // weight products (all f32 via scratch, then 3-plane split)
    mfma_gemm<false><<<dim3(H_ / 128, G4_ / 128), 256, 0, stream>>>(
        whh0, whr0, WF32, G4_, H_, E_, nullptr, nullptr);
    split_planes<<<(G4_ * H_) / 1024, 256, 0, stream>>>(WF32, Wpl0, (size_t)G4_ * H_);

    mfma_gemm<false><<<dim3(H_ / 128, G4_ / 128), 256, 0, stream>>>(
        whh1, whr1, WF32, G4_, H_, E_, nullptr, nullptr);
    split_planes<<<(G4_ * H_) / 1024, 256, 0, stream>>>(WF32, Wpl1, (size_t)G4_ * H_);

    mfma_gemm<false><<<dim3(H_ / 128, G4_ / 128), 256, 0, stream>>>(
        wih1, whr0, WF32, G4_, H_, E_, nullptr, nullptr);
    split_planes<<<(G4_ * H_) / 1024, 256, 0, stream>>>(WF32, WplX, (size_t)G4_ * H_);

    // X0 = seq @ W_ih0^T + b_ih0 + b_hh0, stored [t][col][b]
    xgemm_kernel<<<dim3(G4_ / 128, (T_ * B_) / 128), 256, 0, stream>>>(
        seq, Wpl0, b_ih, b_hh, Xr);
    // NOTE: xgemm's B operand must be W_ih0 planes, not Whhr0!  Build them:
    // (reuse WF32/WplX ordering is wrong — stage W_ih0 planes into scratch area)
    // -- corrected below: we split W_ih0 into a dedicated scratch plane set
    //    placed after seq inside u1ps and re-run xgemm with it.
    {
        unsigned short* WihPl = (unsigned short*)((char*)u1ps + 33947648); // 12.6MB
        split_planes<<<(G4_ * E_) / 1024, 256, 0, stream>>>(wih0, WihPl, (size_t)G4_ * E_);
        xgemm_kernel<<<dim3(G4_ / 128, (T_ * B_) / 128), 256, 0, stream>>>(
            seq, WihPl, b_ih, b_hh, Xr);
    }

    // zero u0(0), u1(0), barrier
    (void)hipMemsetAsync(u0r, 0, SLOT * sizeof(unsigned short), stream);
    (void)hipMemsetAsync(u1ps, 0, SLOT * sizeof(unsigned short), stream);
    (void)hipMemsetAsync(bar, 0, 4096, stream);

    // fused 2-layer pipelined recurrence: one cooperative launch, 129 ticks
    {
        const float* xr_a = Xr;
        const unsigned short* w0_a = Wpl0;
        const unsigned short* wx_a = WplX;
        const unsigned short* w1_a = Wpl1;
        unsigned short* u0_a = u0r;
        unsigned short* u1_a = u1ps;
        const float* bi1_a = b_ih + G4_;
        const float* bh1_a = b_hh + G4_;
        unsigned int* bar_a = bar;
        void* args[] = { (void*)&xr_a, (void*)&w0_a, (void*)&wx_a, (void*)&w1_a,
                         (void*)&u0_a, (void*)&u1_a, (void*)&bi1_a, (void*)&bh1_a,
                         (void*)&bar_a };
        (void)hipLaunchCooperativeKernel((const void*)persistent_lstm,
                                         dim3(256), dim3(512), args, SMEM_BYTES, stream);
    }

    // logits = u1 @ W_hr1^T  -> softmax
    proj_gemm<<<dim3(E_ / 128, (T_ * B_) / 128), 256, 0, stream>>>(u1ps, whr1, logits);
    softmax_kernel<<<(T_ * B_) / 4, 256, 0, stream>>>(logits, out);

    (void)in_sizes; (void)n_in; (void)out_size; (void)ws_size;
}

// Round 12
// 3709.356 us; speedup vs baseline: 1.5445x; 1.5445x over previous
//
#include <hip/hip_runtime.h>
#include <cstdint>
#include <cstddef>

// Problem constants
#define V_ 10000
#define E_ 512
#define H_ 1024
#define L_ 2
#define B_ 64
#define T_ 128
#define G4_ (4 * H_)                 // 4096 gate width
#define SLOT (3 * 128 * 64 * 8)      // shorts per u timestep slot (3 planes)
#define PSTR 65536                   // shorts per u plane (128*64*8)

typedef __attribute__((ext_vector_type(8))) short bf16x8;
typedef __attribute__((ext_vector_type(4))) float f32x4;
typedef __attribute__((ext_vector_type(4))) unsigned int u32x4;

// ---------------------------------------------------------------------------
// bf16 split helpers (RNE; finite values only)
// ---------------------------------------------------------------------------
__device__ __forceinline__ unsigned short f2b(float x) {
    unsigned u = __float_as_uint(x);
    unsigned r = (u + 0x7FFFu + ((u >> 16) & 1u)) >> 16;
    return (unsigned short)r;
}
__device__ __forceinline__ float b2f(unsigned short h) {
    return __uint_as_float(((unsigned)h) << 16);
}
__device__ __forceinline__ void split3(float a, unsigned short& h, unsigned short& l, unsigned short& q) {
    h = f2b(a); float r = a - b2f(h);
    l = f2b(r); float r2 = r - b2f(l);
    q = f2b(r2);
}

// ---------------------------------------------------------------------------
// Embedding + concat: seq (T, B, E) rows m = t*64 + b
// ---------------------------------------------------------------------------
__global__ __launch_bounds__(128) void embed_kernel(
    const float* __restrict__ images, const int* __restrict__ captions,
    const float* __restrict__ table, float* __restrict__ seq)
{
    const int m = blockIdx.x;            // 0..8191
    const int t = m >> 6, b = m & 63;
    const float* src;
    if (t == 0) src = images + (size_t)b * E_;
    else        src = table + (size_t)captions[b * T_ + (t - 1)] * E_;
    float4 v = ((const float4*)src)[threadIdx.x];
    ((float4*)(seq + (size_t)m * E_))[threadIdx.x] = v;
}

// ---------------------------------------------------------------------------
// f32 -> 3 bf16 plane split (plane stride = n elements)
// ---------------------------------------------------------------------------
__global__ __launch_bounds__(256) void split_planes(
    const float* __restrict__ in, unsigned short* __restrict__ pl, size_t n)
{
    size_t i = ((size_t)blockIdx.x * 256 + threadIdx.x) * 4;
    if (i >= n) return;
    float4 v = *(const float4*)&in[i];
    unsigned short h[4], l[4], q[4];
    split3(v.x, h[0], l[0], q[0]); split3(v.y, h[1], l[1], q[1]);
    split3(v.z, h[2], l[2], q[2]); split3(v.w, h[3], l[3], q[3]);
    ushort4 hv = {h[0], h[1], h[2], h[3]};
    ushort4 lv = {l[0], l[1], l[2], l[3]};
    ushort4 qv = {q[0], q[1], q[2], q[3]};
    *(ushort4*)&pl[i]         = hv;
    *(ushort4*)&pl[n + i]     = lv;
    *(ushort4*)&pl[2 * n + i] = qv;
}

// ---------------------------------------------------------------------------
// Split-bf16x6 MFMA GEMM, in-kernel split of both operands.
// Used for weight products (K,N f32 B). C = A(M,K) @ B(K,N), f32 out.
// ---------------------------------------------------------------------------
template<bool BNK>
__global__ __launch_bounds__(256) void mfma_gemm(
    const float* __restrict__ A, const float* __restrict__ Bm, float* __restrict__ C,
    int M, int N, int K,
    const float* __restrict__ bias1, const float* __restrict__ bias2)
{
    __shared__ unsigned short As[3][128][40];
    __shared__ unsigned short Bs[3][128][40];
    const int bm = blockIdx.y * 128, bn = blockIdx.x * 128;
    const int tid = threadIdx.x;
    const int lane = tid & 63, wid = tid >> 6;
    const int wm = wid >> 1, wn = wid & 1;
    const int lr = lane & 15, lk = (lane >> 4) * 8;

    f32x4 acc[4][4] = {};

    for (int k0 = 0; k0 < K; k0 += 32) {
        #pragma unroll
        for (int p = 0; p < 4; ++p) {
            int flat = p * 256 + tid;
            int c4 = flat & 7, r = flat >> 3;
            float4 v = *(const float4*)&A[(size_t)(bm + r) * K + k0 + c4 * 4];
            unsigned short h[4], l[4], q[4];
            split3(v.x, h[0], l[0], q[0]); split3(v.y, h[1], l[1], q[1]);
            split3(v.z, h[2], l[2], q[2]); split3(v.w, h[3], l[3], q[3]);
            unsigned* dh = (unsigned*)&As[0][r][c4 * 4];
            dh[0] = h[0] | ((unsigned)h[1] << 16); dh[1] = h[2] | ((unsigned)h[3] << 16);
            unsigned* dl = (unsigned*)&As[1][r][c4 * 4];
            dl[0] = l[0] | ((unsigned)l[1] << 16); dl[1] = l[2] | ((unsigned)l[3] << 16);
            unsigned* dq = (unsigned*)&As[2][r][c4 * 4];
            dq[0] = q[0] | ((unsigned)q[1] << 16); dq[1] = q[2] | ((unsigned)q[3] << 16);
        }
        if (BNK) {
            #pragma unroll
            for (int p = 0; p < 4; ++p) {
                int flat = p * 256 + tid;
                int c4 = flat & 7, r = flat >> 3;
                float4 v = *(const float4*)&Bm[(size_t)(bn + r) * K + k0 + c4 * 4];
                unsigned short h[4], l[4], q[4];
                split3(v.x, h[0], l[0], q[0]); split3(v.y, h[1], l[1], q[1]);
                split3(v.z, h[2], l[2], q[2]); split3(v.w, h[3], l[3], q[3]);
                unsigned* dh = (unsigned*)&Bs[0][r][c4 * 4];
                dh[0] = h[0] | ((unsigned)h[1] << 16); dh[1] = h[2] | ((unsigned)h[3] << 16);
                unsigned* dl = (unsigned*)&Bs[1][r][c4 * 4];
                dl[0] = l[0] | ((unsigned)l[1] << 16); dl[1] = l[2] | ((unsigned)l[3] << 16);
                unsigned* dq = (unsigned*)&Bs[2][r][c4 * 4];
                dq[0] = q[0] | ((unsigned)q[1] << 16); dq[1] = q[2] | ((unsigned)q[3] << 16);
            }
        } else {
            #pragma unroll
            for (int p = 0; p < 4; ++p) {
                int flat = p * 256 + tid;
                int n4 = flat & 31, kr = flat >> 5;
                float4 v = *(const float4*)&Bm[(size_t)(k0 + kr) * N + bn + n4 * 4];
                float vv[4] = {v.x, v.y, v.z, v.w};
                #pragma unroll
                for (int jj = 0; jj < 4; ++jj) {
                    unsigned short h, l, q; split3(vv[jj], h, l, q);
                    Bs[0][n4 * 4 + jj][kr] = h;
                    Bs[1][n4 * 4 + jj][kr] = l;
                    Bs[2][n4 * 4 + jj][kr] = q;
                }
            }
        }
        __syncthreads();

        bf16x8 af[3][4], bf[3][4];
        #pragma unroll
        for (int pl = 0; pl < 3; ++pl)
            #pragma unroll
            for (int m = 0; m < 4; ++m) {
                af[pl][m] = *(const bf16x8*)&As[pl][wm * 64 + m * 16 + lr][lk];
                bf[pl][m] = *(const bf16x8*)&Bs[pl][wn * 64 + m * 16 + lr][lk];
            }
        #pragma unroll
        for (int m = 0; m < 4; ++m)
            #pragma unroll
            for (int n = 0; n < 4; ++n) {
                acc[m][n] = __builtin_amdgcn_mfma_f32_16x16x32_bf16(af[0][m], bf[0][n], acc[m][n], 0, 0, 0);
                acc[m][n] = __builtin_amdgcn_mfma_f32_16x16x32_bf16(af[0][m], bf[1][n], acc[m][n], 0, 0, 0);
                acc[m][n] = __builtin_amdgcn_mfma_f32_16x16x32_bf16(af[1][m], bf[0][n], acc[m][n], 0, 0, 0);
                acc[m][n] = __builtin_amdgcn_mfma_f32_16x16x32_bf16(af[1][m], bf[1][n], acc[m][n], 0, 0, 0);
                acc[m][n] = __builtin_amdgcn_mfma_f32_16x16x32_bf16(af[0][m], bf[2][n], acc[m][n], 0, 0, 0);
                acc[m][n] = __builtin_amdgcn_mfma_f32_16x16x32_bf16(af[2][m], bf[0][n], acc[m][n], 0, 0, 0);
            }
        __syncthreads();
    }

    float bv[4];
    #pragma unroll
    for (int n = 0; n < 4; ++n) {
        int col = bn + wn * 64 + n * 16 + lr;
        float x = 0.f;
        if (bias1) x += bias1[col];
        if (bias2) x += bias2[col];
        bv[n] = x;
    }
    #pragma unroll
    for (int m = 0; m < 4; ++m) {
        int rbase = bm + wm * 64 + m * 16 + (lane >> 4) * 4;
        #pragma unroll
        for (int n = 0; n < 4; ++n) {
            int col = bn + wn * 64 + n * 16 + lr;
            #pragma unroll
            for (int r = 0; r < 4; ++r)
                C[(size_t)(rbase + r) * N + col] = acc[m][n][r] + bv[n];
        }
    }
}

// ---------------------------------------------------------------------------
// X GEMM (layer 0 only): Xr[t][col][b] = seq(8192,512) @ W_ih0^T + b0
// ---------------------------------------------------------------------------
__global__ __launch_bounds__(256) void xgemm_kernel(
    const float* __restrict__ A, const unsigned short* __restrict__ Bpl,
    const float* __restrict__ bias1, const float* __restrict__ bias2,
    float* __restrict__ Xr)
{
    __shared__ unsigned short As[3][128][40];
    __shared__ unsigned short Bs[3][128][40];
    const int bm = blockIdx.y * 128, bn = blockIdx.x * 128;
    const int tid = threadIdx.x;
    const int lane = tid & 63, wid = tid >> 6;
    const int wm = wid >> 1, wn = wid & 1;
    const int lr = lane & 15, lg = lane >> 4, lk = lg * 8;

    f32x4 acc[4][4] = {};

    for (int k0 = 0; k0 < E_; k0 += 32) {
        #pragma unroll
        for (int p = 0; p < 4; ++p) {
            int flat = p * 256 + tid;
            int c4 = flat & 7, r = flat >> 3;
            float4 v = *(const float4*)&A[(size_t)(bm + r) * E_ + k0 + c4 * 4];
            unsigned short h[4], l[4], q[4];
            split3(v.x, h[0], l[0], q[0]); split3(v.y, h[1], l[1], q[1]);
            split3(v.z, h[2], l[2], q[2]); split3(v.w, h[3], l[3], q[3]);
            unsigned* dh = (unsigned*)&As[0][r][c4 * 4];
            dh[0] = h[0] | ((unsigned)h[1] << 16); dh[1] = h[2] | ((unsigned)h[3] << 16);
            unsigned* dl = (unsigned*)&As[1][r][c4 * 4];
            dl[0] = l[0] | ((unsigned)l[1] << 16); dl[1] = l[2] | ((unsigned)l[3] << 16);
            unsigned* dq = (unsigned*)&As[2][r][c4 * 4];
            dq[0] = q[0] | ((unsigned)q[1] << 16); dq[1] = q[2] | ((unsigned)q[3] << 16);
        }
        #pragma unroll
        for (int p6 = 0; p6 < 6; ++p6) {
            int f = p6 * 256 + tid;
            int pl = f >> 9, rem = f & 511;
            int r = rem >> 2, g4 = rem & 3;
            const unsigned short* src = Bpl + (size_t)pl * (G4_ * E_) + (size_t)(bn + r) * E_ + k0 + g4 * 8;
            *(uint4*)&Bs[pl][r][g4 * 8] = *(const uint4*)src;
        }
        __syncthreads();

        bf16x8 af[3][4], bf[3][4];
        #pragma unroll
        for (int pl = 0; pl < 3; ++pl)
            #pragma unroll
            for (int m = 0; m < 4; ++m) {
                af[pl][m] = *(const bf16x8*)&As[pl][wm * 64 + m * 16 + lr][lk];
                bf[pl][m] = *(const bf16x8*)&Bs[pl][wn * 64 + m * 16 + lr][lk];
            }
        #pragma unroll
        for (int m = 0; m < 4; ++m)
            #pragma unroll
            for (int n = 0; n < 4; ++n) {
                acc[m][n] = __builtin_amdgcn_mfma_f32_16x16x32_bf16(af[0][m], bf[0][n], acc[m][n], 0, 0, 0);
                acc[m][n] = __builtin_amdgcn_mfma_f32_16x16x32_bf16(af[0][m], bf[1][n], acc[m][n], 0, 0, 0);
                acc[m][n] = __builtin_amdgcn_mfma_f32_16x16x32_bf16(af[1][m], bf[0][n], acc[m][n], 0, 0, 0);
                acc[m][n] = __builtin_amdgcn_mfma_f32_16x16x32_bf16(af[1][m], bf[1][n], acc[m][n], 0, 0, 0);
                acc[m][n] = __builtin_amdgcn_mfma_f32_16x16x32_bf16(af[0][m], bf[2][n], acc[m][n], 0, 0, 0);
                acc[m][n] = __builtin_amdgcn_mfma_f32_16x16x32_bf16(af[2][m], bf[0][n], acc[m][n], 0, 0, 0);
            }
        __syncthreads();
    }

    #pragma unroll
    for (int n = 0; n < 4; ++n) {
        int col = bn + wn * 64 + n * 16 + lr;
        float bv = bias1[col] + bias2[col];
        #pragma unroll
        for (int m = 0; m < 4; ++m) {
            int rbase = bm + wm * 64 + m * 16 + lg * 4;
            #pragma unroll
            for (int r = 0; r < 4; ++r) {
                int row = rbase + r;
                Xr[((size_t)(row >> 6) * G4_ + col) * 64 + (row & 63)] = acc[m][n][r] + bv;
            }
        }
    }
}

// ---------------------------------------------------------------------------
// Fused 2-layer pipelined LSTM recurrence: 256 blocks x 512 threads, 129 ticks.
// Blocks 0-127: layer 0. Blocks 128-255: layer 1 lagged 1 tick:
//   gates1 = u0(t)@Wx1^T + u1(t-1)@Whhr1^T + b1   (Wx1 = W_ih1@W_hr0).
// R12: recurrence uses 5-product split (hh,hl,lh,ll,hq) — weight q-planes
// NOT streamed (residual ~3e-7/gate, margin-safe). L0: hi+lo in LDS, zero
// weight streams. L1: hi of both mats in LDS, lo streamed (L2-resident,
// 2MB/XCD). Barrier/coherence: R10-proven (sc0sc1 write-through u stores +
// vmcnt drain; relaxed direct-poll barrier, 32 counters x 8 blocks).
// ---------------------------------------------------------------------------
__global__ __launch_bounds__(512, 1) void persistent_lstm(
    const float* __restrict__ Xr,               // [128][4096][64]
    const unsigned short* __restrict__ Wpl0,    // [3][4096*1024] layer0 Whhr
    const unsigned short* __restrict__ WplX,    // [3][4096*1024] Wx1
    const unsigned short* __restrict__ Wpl1,    // [3][4096*1024] layer1 Whhr
    unsigned short* __restrict__ u0r,           // [2][SLOT] ring
    unsigned short* __restrict__ u1ps,          // [129][SLOT]
    const float* __restrict__ bih1,
    const float* __restrict__ bhh1,
    unsigned int* bar)                          // 32 counters, 64B apart
{
    extern __shared__ unsigned short smem[];
    unsigned short* Wlds = smem;                // 131072 B
    unsigned short* u_sm = smem + 65536;        // 3072 B
    float* psum = (float*)(smem + 67072);       // 8192 B

    const int tid = threadIdx.x;
    const int j = blockIdx.x;                   // 0..255
    const int wid = tid >> 6, lane = tid & 63;
    const int grp = wid >> 2, bq = wid & 3;     // L0: k-half; L1: matrix
    const int lr = lane & 15, lg = lane >> 4;
    const bool isL0 = (j < 128);
    const int jj = isL0 ? j : (j - 128);
    const int b = bq * 16 + lr;
    const int uoff = b * 8;
    const int swzb = lr & 7;
    const int gr0 = (lr & 3) * 1024 + jj * 8 + (lr >> 2);
    const int gr1 = gr0 + 4;

    float c0 = 0.f, c1 = 0.f;
    float b1v0[4], b1v1[4];

    if (isL0) {
        // stage hi/lo planes of Whhr0's 32 gate-rows (R10-exact)
        for (int it = 0; it < 16; ++it) {
            int f = it * 512 + tid;
            int p = f >> 12;
            int rem = f & 4095;
            int h2 = rem >> 11;
            int rem2 = rem & 2047;
            int n = rem2 >> 7;
            int g16 = rem2 & 127;
            int gr = (n & 3) * 1024 + jj * 8 + h2 * 4 + (n >> 2);
            const unsigned short* src = Wpl0 + (size_t)p * (G4_ * H_) + (size_t)gr * H_ + g16 * 8;
            *(uint4*)&Wlds[(size_t)((p * 2 + h2) * 16 + n) * 1024 + (g16 ^ (n & 7)) * 8] = *(const uint4*)src;
        }
    } else {
        // stage hi planes of BOTH matrices (Wx1, Whhr1): [mat][h2][16][1024]
        for (int it = 0; it < 16; ++it) {
            int f = it * 512 + tid;
            int m = f >> 12;
            int rem = f & 4095;
            int h2 = rem >> 11;
            int rem2 = rem & 2047;
            int n = rem2 >> 7;
            int g16 = rem2 & 127;
            int gr = (n & 3) * 1024 + jj * 8 + h2 * 4 + (n >> 2);
            const unsigned short* base = (m == 0) ? WplX : Wpl1;
            const unsigned short* src = base + (size_t)gr * H_ + g16 * 8;   // plane 0 = hi
            *(uint4*)&Wlds[(size_t)((m * 2 + h2) * 16 + n) * 1024 + (g16 ^ (n & 7)) * 8] = *(const uint4*)src;
        }
        #pragma unroll
        for (int g = 0; g < 4; ++g) {
            int idx = g * 1024 + jj * 8 + lg;
            b1v0[g] = bih1[idx] + bhh1[idx];
            b1v1[g] = bih1[idx + 4] + bhh1[idx + 4];
        }
    }
    __syncthreads();

    // L1 streamed lo rows of this wave's matrix (plane 1)
    const unsigned short* mbase = (grp == 0) ? WplX : Wpl1;
    const unsigned short* ml0 = mbase + (size_t)1 * (G4_ * H_) + (size_t)gr0 * H_;
    const unsigned short* ml1 = mbase + (size_t)1 * (G4_ * H_) + (size_t)gr1 * H_;

    for (int tau = 0; tau <= T_; ++tau) {
        if (isL0) {
            if (tau < T_) {
                const int t = tau;
                const unsigned short* ut = u0r + (size_t)(t & 1) * SLOT;
                float xg0[4], xg1[4];
                if (grp == 0) {
                    #pragma unroll
                    for (int g = 0; g < 4; ++g) {
                        xg0[g] = Xr[((size_t)t * G4_ + g * 1024 + jj * 8 + lg) * 64 + b];
                        xg1[g] = Xr[((size_t)t * G4_ + g * 1024 + jj * 8 + 4 + lg) * 64 + b];
                    }
                }
                f32x4 a0 = {0.f,0.f,0.f,0.f}, p0 = {0.f,0.f,0.f,0.f};
                f32x4 a1 = {0.f,0.f,0.f,0.f}, p1 = {0.f,0.f,0.f,0.f};
                const int kbase = grp * 64;
                #pragma unroll 8
                for (int ks = 0; ks < 16; ++ks) {
                    int g16 = kbase + ks * 4 + lg;
                    int swz = (g16 ^ swzb) * 8;
                    bf16x8 uh = *(const bf16x8*)&ut[(size_t)g16 * 512 + uoff];
                    bf16x8 ul = *(const bf16x8*)&ut[PSTR + (size_t)g16 * 512 + uoff];
                    bf16x8 uq = *(const bf16x8*)&ut[2 * PSTR + (size_t)g16 * 512 + uoff];
                    bf16x8 wh0 = *(const bf16x8*)&Wlds[(size_t)(0 * 16 + lr) * 1024 + swz];
                    bf16x8 wh1 = *(const bf16x8*)&Wlds[(size_t)(1 * 16 + lr) * 1024 + swz];
                    bf16x8 wl0 = *(const bf16x8*)&Wlds[(size_t)(2 * 16 + lr) * 1024 + swz];
                    bf16x8 wl1 = *(const bf16x8*)&Wlds[(size_t)(3 * 16 + lr) * 1024 + swz];
                    a0 = __builtin_amdgcn_mfma_f32_16x16x32_bf16(wh0, uh, a0, 0, 0, 0);
                    a0 = __builtin_amdgcn_mfma_f32_16x16x32_bf16(wh0, ul, a0, 0, 0, 0);
                    a0 = __builtin_amdgcn_mfma_f32_16x16x32_bf16(wl0, uh, a0, 0, 0, 0);
                    p0 = __builtin_amdgcn_mfma_f32_16x16x32_bf16(wl0, ul, p0, 0, 0, 0);
                    p0 = __builtin_amdgcn_mfma_f32_16x16x32_bf16(wh0, uq, p0, 0, 0, 0);
                    a1 = __builtin_amdgcn_mfma_f32_16x16x32_bf16(wh1, uh, a1, 0, 0, 0);
                    a1 = __builtin_amdgcn_mfma_f32_16x16x32_bf16(wh1, ul, a1, 0, 0, 0);
                    a1 = __builtin_amdgcn_mfma_f32_16x16x32_bf16(wl1, uh, a1, 0, 0, 0);
                    p1 = __builtin_amdgcn_mfma_f32_16x16x32_bf16(wl1, ul, p1, 0, 0, 0);
                    p1 = __builtin_amdgcn_mfma_f32_16x16x32_bf16(wh1, uq, p1, 0, 0, 0);
                }
                if (grp == 1) {
                    float* pp = &psum[(size_t)(bq * 64 + lane) * 8];
                    *(f32x4*)&pp[0] = a0 + p0;
                    *(f32x4*)&pp[4] = a1 + p1;
                }
                __syncthreads();
                if (grp == 0) {
                    const float* pp = &psum[(size_t)(bq * 64 + lane) * 8];
                    f32x4 s0o = *(const f32x4*)&pp[0];
                    f32x4 s1o = *(const f32x4*)&pp[4];
                    {
                        float gi = a0[0]+p0[0]+s0o[0]+xg0[0];
                        float gf = a0[1]+p0[1]+s0o[1]+xg0[1];
                        float gv = a0[2]+p0[2]+s0o[2]+xg0[2];
                        float go = a0[3]+p0[3]+s0o[3]+xg0[3];
                        float si = 1.f/(1.f+__expf(-gi));
                        float sf = 1.f/(1.f+__expf(-gf));
                        float so = 1.f/(1.f+__expf(-go));
                        c0 = sf*c0 + si*tanhf(gv);
                        float ho = so*tanhf(c0);
                        unsigned short sh, sl, sq; split3(ho, sh, sl, sq);
                        u_sm[(0*64+b)*8+lg] = sh; u_sm[(1*64+b)*8+lg] = sl; u_sm[(2*64+b)*8+lg] = sq;
                    }
                    {
                        float gi = a1[0]+p1[0]+s1o[0]+xg1[0];
                        float gf = a1[1]+p1[1]+s1o[1]+xg1[1];
                        float gv = a1[2]+p1[2]+s1o[2]+xg1[2];
                        float go = a1[3]+p1[3]+s1o[3]+xg1[3];
                        float si = 1.f/(1.f+__expf(-gi));
                        float sf = 1.f/(1.f+__expf(-gf));
                        float so = 1.f/(1.f+__expf(-go));
                        c1 = sf*c1 + si*tanhf(gv);
                        float ho = so*tanhf(c1);
                        unsigned short sh, sl, sq; split3(ho, sh, sl, sq);
                        u_sm[(0*64+b)*8+4+lg] = sh; u_sm[(1*64+b)*8+4+lg] = sl; u_sm[(2*64+b)*8+4+lg] = sq;
                    }
                }
                __syncthreads();
                if (tid < 192) {
                    int pl = tid >> 6, bb = tid & 63;
                    u32x4 v = *(const u32x4*)&u_sm[(pl * 64 + bb) * 8];
                    unsigned short* dst = u0r + (size_t)((t + 1) & 1) * SLOT
                                        + (size_t)pl * PSTR + (size_t)(jj * 64 + bb) * 8;
                    asm volatile("global_store_dwordx4 %0, %1, off sc0 sc1"
                                 :: "v"(dst), "v"(v) : "memory");
                }
            }
        } else {
            if (tau >= 1) {
                const int t = tau;
                const unsigned short* u0b = u0r + (size_t)(t & 1) * SLOT;      // u0(t)
                const unsigned short* u1b = u1ps + (size_t)(t - 1) * SLOT;     // u1(t-1)
                const unsigned short* ub = (grp == 0) ? u0b : u1b;
                f32x4 a0 = {0.f,0.f,0.f,0.f}, p0 = {0.f,0.f,0.f,0.f};
                f32x4 a1 = {0.f,0.f,0.f,0.f}, p1 = {0.f,0.f,0.f,0.f};
                const int lbase = grp * 32;   // LDS row base for this matrix
                #pragma unroll 8
                for (int ks = 0; ks < 32; ++ks) {
                    int g16 = ks * 4 + lg;
                    int swz = (g16 ^ swzb) * 8;
                    bf16x8 uh = *(const bf16x8*)&ub[(size_t)g16 * 512 + uoff];
                    bf16x8 ul = *(const bf16x8*)&ub[PSTR + (size_t)g16 * 512 + uoff];
                    bf16x8 uq = *(const bf16x8*)&ub[2 * PSTR + (size_t)g16 * 512 + uoff];
                    bf16x8 wh0 = *(const bf16x8*)&Wlds[(size_t)(lbase + lr) * 1024 + swz];
                    bf16x8 wh1 = *(const bf16x8*)&Wlds[(size_t)(lbase + 16 + lr) * 1024 + swz];
                    bf16x8 wl0v = *(const bf16x8*)&ml0[g16 * 8];
                    bf16x8 wl1v = *(const bf16x8*)&ml1[g16 * 8];
                    a0 = __builtin_amdgcn_mfma_f32_16x16x32_bf16(wh0, uh, a0, 0, 0, 0);
                    a0 = __builtin_amdgcn_mfma_f32_16x16x32_bf16(wh0, ul, a0, 0, 0, 0);
                    a0 = __builtin_amdgcn_mfma_f32_16x16x32_bf16(wl0v, uh, a0, 0, 0, 0);
                    p0 = __builtin_amdgcn_mfma_f32_16x16x32_bf16(wl0v, ul, p0, 0, 0, 0);
                    p0 = __builtin_amdgcn_mfma_f32_16x16x32_bf16(wh0, uq, p0, 0, 0, 0);
                    a1 = __builtin_amdgcn_mfma_f32_16x16x32_bf16(wh1, uh, a1, 0, 0, 0);
                    a1 = __builtin_amdgcn_mfma_f32_16x16x32_bf16(wh1, ul, a1, 0, 0, 0);
                    a1 = __builtin_amdgcn_mfma_f32_16x16x32_bf16(wl1v, uh, a1, 0, 0, 0);
                    p1 = __builtin_amdgcn_mfma_f32_16x16x32_bf16(wl1v, ul, p1, 0, 0, 0);
                    p1 = __builtin_amdgcn_mfma_f32_16x16x32_bf16(wh1, uq, p1, 0, 0, 0);
                }
                if (grp == 1) {
                    float* pp = &psum[(size_t)(bq * 64 + lane) * 8];
                    *(f32x4*)&pp[0] = a0 + p0;
                    *(f32x4*)&pp[4] = a1 + p1;
                }
                __syncthreads();
                if (grp == 0) {
                    const float* pp = &psum[(size_t)(bq * 64 + lane) * 8];
                    f32x4 s0o = *(const f32x4*)&pp[0];
                    f32x4 s1o = *(const f32x4*)&pp[4];
                    {
                        float gi = a0[0]+p0[0]+s0o[0]+b1v0[0];
                        float gf = a0[1]+p0[1]+s0o[1]+b1v0[1];
                        float gv = a0[2]+p0[2]+s0o[2]+b1v0[2];
                        float go = a0[3]+p0[3]+s0o[3]+b1v0[3];
                        float si = 1.f/(1.f+__expf(-gi));
                        float sf = 1.f/(1.f+__expf(-gf));
                        float so = 1.f/(1.f+__expf(-go));
                        c0 = sf*c0 + si*tanhf(gv);
                        float ho = so*tanhf(c0);
                        unsigned short sh, sl, sq; split3(ho, sh, sl, sq);
                        u_sm[(0*64+b)*8+lg] = sh; u_sm[(1*64+b)*8+lg] = sl; u_sm[(2*64+b)*8+lg] = sq;
                    }
                    {
                        float gi = a1[0]+p1[0]+s1o[0]+b1v1[0];
                        float gf = a1[1]+p1[1]+s1o[1]+b1v1[1];
                        float gv = a1[2]+p1[2]+s1o[2]+b1v1[2];
                        float go = a1[3]+p1[3]+s1o[3]+b1v1[3];
                        float si = 1.f/(1.f+__expf(-gi));
                        float sf = 1.f/(1.f+__expf(-gf));
                        float so = 1.f/(1.f+__expf(-go));
                        c1 = sf*c1 + si*tanhf(gv);
                        float ho = so*tanhf(c1);
                        unsigned short sh, sl, sq; split3(ho, sh, sl, sq);
                        u_sm[(0*64+b)*8+4+lg] = sh; u_sm[(1*64+b)*8+4+lg] = sl; u_sm[(2*64+b)*8+4+lg] = sq;
                    }
                }
                __syncthreads();
                if (tid < 192) {
                    int pl = tid >> 6, bb = tid & 63;
                    u32x4 v = *(const u32x4*)&u_sm[(pl * 64 + bb) * 8];
                    unsigned short* dst = u1ps + (size_t)t * SLOT
                                        + (size_t)pl * PSTR + (size_t)(jj * 64 + bb) * 8;
                    asm volatile("global_store_dwordx4 %0, %1, off sc0 sc1"
                                 :: "v"(dst), "v"(v) : "memory");
                }
            }
        }

        if (tau < T_) {
            asm volatile("s_waitcnt vmcnt(0)" ::: "memory");
            __syncthreads();
            if (tid == 0)
                __hip_atomic_fetch_add(&bar[(j & 31) * 16], 1u,
                                       __ATOMIC_RELAXED, __HIP_MEMORY_SCOPE_AGENT);
            if (tid < 32) {
                const unsigned tgt = (unsigned)(tau + 1) * 8u;
                while (__hip_atomic_load(&bar[tid * 16],
                                         __ATOMIC_RELAXED, __HIP_MEMORY_SCOPE_AGENT) < tgt) {}
            }
            __syncthreads();
        }
    }
}

// ---------------------------------------------------------------------------
// Projection GEMM: logits(8192,512) = U1(8192,1024) @ W_hr1^T
// ---------------------------------------------------------------------------
__global__ __launch_bounds__(256) void proj_gemm(
    const unsigned short* __restrict__ u_ps,   // [129][SLOT]
    const float* __restrict__ Whr,             // (512,1024) f32 (N,K)
    float* __restrict__ C)                     // (8192,512)
{
    __shared__ unsigned short Bs[3][128][40];
    const int bn = blockIdx.x * 128;
    const int bm = blockIdx.y * 128;
    const int tid = threadIdx.x;
    const int lane = tid & 63, wid = tid >> 6;
    const int wm = wid >> 1, wn = wid & 1;
    const int lr = lane & 15, lg = lane >> 4, lk = lg * 8;

    f32x4 acc[4][4] = {};
    const int t = (bm >> 6) + wm;
    const unsigned short* ut = u_ps + (size_t)(t + 1) * SLOT;

    for (int k0 = 0; k0 < H_; k0 += 32) {
        #pragma unroll
        for (int p = 0; p < 4; ++p) {
            int flat = p * 256 + tid;
            int c4 = flat & 7, r = flat >> 3;
            float4 v = *(const float4*)&Whr[(size_t)(bn + r) * H_ + k0 + c4 * 4];
            unsigned short h[4], l[4], q[4];
            split3(v.x, h[0], l[0], q[0]); split3(v.y, h[1], l[1], q[1]);
            split3(v.z, h[2], l[2], q[2]); split3(v.w, h[3], l[3], q[3]);
            unsigned* dh = (unsigned*)&Bs[0][r][c4 * 4];
            dh[0] = h[0] | ((unsigned)h[1] << 16); dh[1] = h[2] | ((unsigned)h[3] << 16);
            unsigned* dl = (unsigned*)&Bs[1][r][c4 * 4];
            dl[0] = l[0] | ((unsigned)l[1] << 16); dl[1] = l[2] | ((unsigned)l[3] << 16);
            unsigned* dq = (unsigned*)&Bs[2][r][c4 * 4];
            dq[0] = q[0] | ((unsigned)q[1] << 16); dq[1] = q[2] | ((unsigned)q[3] << 16);
        }
        __syncthreads();

        int ks = k0 >> 5;
        bf16x8 af[3][4], bf[3][4];
        #pragma unroll
        for (int pl = 0; pl < 3; ++pl)
            #pragma unroll
            for (int m = 0; m < 4; ++m) {
                af[pl][m] = *(const bf16x8*)&ut[(size_t)pl * PSTR + (size_t)((ks * 4 + lg) * 64 + m * 16 + lr) * 8];
                bf[pl][m] = *(const bf16x8*)&Bs[pl][wn * 64 + m * 16 + lr][lk];
            }
        #pragma unroll
        for (int m = 0; m < 4; ++m)
            #pragma unroll
            for (int n = 0; n < 4; ++n) {
                acc[m][n] = __builtin_amdgcn_mfma_f32_16x16x32_bf16(af[0][m], bf[0][n], acc[m][n], 0, 0, 0);
                acc[m][n] = __builtin_amdgcn_mfma_f32_16x16x32_bf16(af[0][m], bf[1][n], acc[m][n], 0, 0, 0);
                acc[m][n] = __builtin_amdgcn_mfma_f32_16x16x32_bf16(af[1][m], bf[0][n], acc[m][n], 0, 0, 0);
                acc[m][n] = __builtin_amdgcn_mfma_f32_16x16x32_bf16(af[1][m], bf[1][n], acc[m][n], 0, 0, 0);
                acc[m][n] = __builtin_amdgcn_mfma_f32_16x16x32_bf16(af[0][m], bf[2][n], acc[m][n], 0, 0, 0);
                acc[m][n] = __builtin_amdgcn_mfma_f32_16x16x32_bf16(af[2][m], bf[0][n], acc[m][n], 0, 0, 0);
            }
        __syncthreads();
    }

    #pragma unroll
    for (int m = 0; m < 4; ++m) {
        int rbase = bm + wm * 64 + m * 16 + lg * 4;
        #pragma unroll
        for (int n = 0; n < 4; ++n) {
            int col = bn + wn * 64 + n * 16 + lr;
            #pragma unroll
            for (int r = 0; r < 4; ++r)
                C[(size_t)(rbase + r) * E_ + col] = acc[m][n][r];
        }
    }
}

// ---------------------------------------------------------------------------
// Row softmax over E=512; input rows m = t*64+b, output row (b, t).
// ---------------------------------------------------------------------------
__global__ __launch_bounds__(256) void softmax_kernel(
    const float* __restrict__ LOG, float* __restrict__ out)
{
    const int lane = threadIdx.x & 63;
    const int r = blockIdx.x * 4 + (threadIdx.x >> 6);
    const float* src = LOG + (size_t)r * E_;
    float v[8];
    *(float4*)&v[0] = ((const float4*)src)[lane * 2];
    *(float4*)&v[4] = ((const float4*)src)[lane * 2 + 1];

    float m = v[0];
    #pragma unroll
    for (int i = 1; i < 8; ++i) m = fmaxf(m, v[i]);
    #pragma unroll
    for (int off = 32; off > 0; off >>= 1) m = fmaxf(m, __shfl_xor(m, off, 64));

    float s = 0.f;
    #pragma unroll
    for (int i = 0; i < 8; ++i) { v[i] = expf(v[i] - m); s += v[i]; }
    #pragma unroll
    for (int off = 32; off > 0; off >>= 1) s += __shfl_xor(s, off, 64);
    const float inv = 1.f / s;

    const int t = r >> 6, b = r & 63;
    float* dst = out + ((size_t)b * T_ + t) * E_;
    #pragma unroll
    for (int i = 0; i < 8; ++i) v[i] *= inv;
    ((float4*)dst)[lane * 2]     = *(float4*)&v[0];
    ((float4*)dst)[lane * 2 + 1] = *(float4*)&v[4];
}

// ---------------------------------------------------------------------------
extern "C" void kernel_launch(void* const* d_in, const int* in_sizes, int n_in,
                              void* d_out, int out_size, void* d_ws, size_t ws_size,
                              hipStream_t stream)
{
    const float* images   = (const float*)d_in[0];
    const int*   captions = (const int*)  d_in[1];
    const float* table    = (const float*)d_in[2];
    const float* W_ih     = (const float*)d_in[3];
    const float* W_hh     = (const float*)d_in[4];
    const float* W_hr     = (const float*)d_in[5];
    const float* b_ih     = (const float*)d_in[6];
    const float* b_hh     = (const float*)d_in[7];
    float* out = (float*)d_out;

    // Workspace layout (byte offsets)
    char* base = (char*)d_ws;
    float*          Xr    = (float*)base;                            // 134,217,728
    unsigned int*   bar   = (unsigned int*)(base + 134217728);       //       4,096
    unsigned short* u0r   = (unsigned short*)(base + 134221824);     //     786,432 (2 slots)
    unsigned short* u1ps  = (unsigned short*)(base + 135008256);     //  50,724,864 (129 slots)
    unsigned short* Wpl0  = (unsigned short*)(base + 185733120);     //  25,165,824
    unsigned short* Wpl1  = (unsigned short*)(base + 210898944);     //  25,165,824
    unsigned short* WplX  = (unsigned short*)(base + 236064768);     //  25,165,824
    // sequentially-dead aliases inside u1ps (overwritten later by coop kernel)
    float* WF32 = (float*)((char*)u1ps + 393216);                    // 16.8MB scratch
    float* seq  = (float*)((char*)u1ps + 17170432);                  // 16.8MB
    float* logits = Xr;

    const int SMEM_BYTES = 131072 + 3072 + 8192;
    (void)hipFuncSetAttribute((const void*)persistent_lstm,
                              hipFuncAttributeMaxDynamicSharedMemorySize, SMEM_BYTES);

    const float* wih0 = W_ih;
    const float* wih1 = W_ih + (size_t)G4_ * E_;
    const float* whh0 = W_hh;
    const float* whh1 = W_hh + (size_t)G4_ * E_;
    const float* whr0 = W_hr;
    const float* whr1 = W_hr + (size_t)E_ * H_;

    embed_kernel<<<T_ * B_, 128, 0, stream>>>(images, captions, table, seq);

    // weight products (all f32 via scratch, then 3-plane split)
    mfma_gemm<false><<<dim3(H_ / 128, G4_ / 128), 256, 0, stream>>>(
        whh0, whr0, WF32, G4_, H_, E_, nullptr, nullptr);
    split_planes<<<(G4_ * H_) / 1024, 256, 0, stream>>>(WF32, Wpl0, (size_t)G4_ * H_);

    mfma_gemm<false><<<dim3(H_ / 128, G4_ / 128), 256, 0, stream>>>(
        whh1, whr1, WF32, G4_, H_, E_, nullptr, nullptr);
    split_planes<<<(G4_ * H_) / 1024, 256, 0, stream>>>(WF32, Wpl1, (size_t)G4_ * H_);

    mfma_gemm<false><<<dim3(H_ / 128, G4_ / 128), 256, 0, stream>>>(
        wih1, whr0, WF32, G4_, H_, E_, nullptr, nullptr);
    split_planes<<<(G4_ * H_) / 1024, 256, 0, stream>>>(WF32, WplX, (size_t)G4_ * H_);

    // X0 = seq @ W_ih0^T + b_ih0 + b_hh0, stored [t][col][b]
    {
        unsigned short* WihPl = (unsigned short*)((char*)u1ps + 33947648); // 12.6MB
        split_planes<<<(G4_ * E_) / 1024, 256, 0, stream>>>(wih0, WihPl, (size_t)G4_ * E_);
        xgemm_kernel<<<dim3(G4_ / 128, (T_ * B_) / 128), 256, 0, stream>>>(
            seq, WihPl, b_ih, b_hh, Xr);
    }

    // zero u0(0), u1(0), barrier
    (void)hipMemsetAsync(u0r, 0, SLOT * sizeof(unsigned short), stream);
    (void)hipMemsetAsync(u1ps, 0, SLOT * sizeof(unsigned short), stream);
    (void)hipMemsetAsync(bar, 0, 4096, stream);

    // fused 2-layer pipelined recurrence: one cooperative launch, 129 ticks
    {
        const float* xr_a = Xr;
        const unsigned short* w0_a = Wpl0;
        const unsigned short* wx_a = WplX;
        const unsigned short* w1_a = Wpl1;
        unsigned short* u0_a = u0r;
        unsigned short* u1_a = u1ps;
        const float* bi1_a = b_ih + G4_;
        const float* bh1_a = b_hh + G4_;
        unsigned int* bar_a = bar;
        void* args[] = { (void*)&xr_a, (void*)&w0_a, (void*)&wx_a, (void*)&w1_a,
                         (void*)&u0_a, (void*)&u1_a, (void*)&bi1_a, (void*)&bh1_a,
                         (void*)&bar_a };
        (void)hipLaunchCooperativeKernel((const void*)persistent_lstm,
                                         dim3(256), dim3(512), args, SMEM_BYTES, stream);
    }

    // logits = u1 @ W_hr1^T  -> softmax
    proj_gemm<<<dim3(E_ / 128, (T_ * B_) / 128), 256, 0, stream>>>(u1ps, whr1, logits);
    softmax_kernel<<<(T_ * B_) / 4, 256, 0, stream>>>(logits, out);

    (void)in_sizes; (void)n_in; (void)out_size; (void)ws_size;
}

// Round 13
// 2832.407 us; speedup vs baseline: 2.0227x; 1.3096x over previous
//
#include <hip/hip_runtime.h>
#include <cstdint>
#include <cstddef>

// Problem constants
#define V_ 10000
#define E_ 512
#define H_ 1024
#define L_ 2
#define B_ 64
#define T_ 128
#define G4_ (4 * H_)                 // 4096 gate width
#define SLOT (3 * 128 * 64 * 8)      // shorts per u timestep slot (3 planes)
#define PSTR 65536                   // shorts per u plane (128*64*8)

typedef __attribute__((ext_vector_type(8))) short bf16x8;
typedef __attribute__((ext_vector_type(4))) float f32x4;
typedef __attribute__((ext_vector_type(4))) unsigned int u32x4;

// ---------------------------------------------------------------------------
// bf16 split helpers (RNE; finite values only)
// ---------------------------------------------------------------------------
__device__ __forceinline__ unsigned short f2b(float x) {
    unsigned u = __float_as_uint(x);
    unsigned r = (u + 0x7FFFu + ((u >> 16) & 1u)) >> 16;
    return (unsigned short)r;
}
__device__ __forceinline__ float b2f(unsigned short h) {
    return __uint_as_float(((unsigned)h) << 16);
}
__device__ __forceinline__ void split3(float a, unsigned short& h, unsigned short& l, unsigned short& q) {
    h = f2b(a); float r = a - b2f(h);
    l = f2b(r); float r2 = r - b2f(l);
    q = f2b(r2);
}

// ---------------------------------------------------------------------------
// Embedding + concat: seq (T, B, E) rows m = t*64 + b
// ---------------------------------------------------------------------------
__global__ __launch_bounds__(128) void embed_kernel(
    const float* __restrict__ images, const int* __restrict__ captions,
    const float* __restrict__ table, float* __restrict__ seq)
{
    const int m = blockIdx.x;            // 0..8191
    const int t = m >> 6, b = m & 63;
    const float* src;
    if (t == 0) src = images + (size_t)b * E_;
    else        src = table + (size_t)captions[b * T_ + (t - 1)] * E_;
    float4 v = ((const float4*)src)[threadIdx.x];
    ((float4*)(seq + (size_t)m * E_))[threadIdx.x] = v;
}

// ---------------------------------------------------------------------------
// f32 -> 3 bf16 plane split (plane stride = n elements)
// ---------------------------------------------------------------------------
__global__ __launch_bounds__(256) void split_planes(
    const float* __restrict__ in, unsigned short* __restrict__ pl, size_t n)
{
    size_t i = ((size_t)blockIdx.x * 256 + threadIdx.x) * 4;
    if (i >= n) return;
    float4 v = *(const float4*)&in[i];
    unsigned short h[4], l[4], q[4];
    split3(v.x, h[0], l[0], q[0]); split3(v.y, h[1], l[1], q[1]);
    split3(v.z, h[2], l[2], q[2]); split3(v.w, h[3], l[3], q[3]);
    ushort4 hv = {h[0], h[1], h[2], h[3]};
    ushort4 lv = {l[0], l[1], l[2], l[3]};
    ushort4 qv = {q[0], q[1], q[2], q[3]};
    *(ushort4*)&pl[i]         = hv;
    *(ushort4*)&pl[n + i]     = lv;
    *(ushort4*)&pl[2 * n + i] = qv;
}

// ---------------------------------------------------------------------------
// Split-bf16x6 MFMA GEMM, in-kernel split of both operands.
// Used for weight products (K,N f32 B). C = A(M,K) @ B(K,N), f32 out.
// ---------------------------------------------------------------------------
template<bool BNK>
__global__ __launch_bounds__(256) void mfma_gemm(
    const float* __restrict__ A, const float* __restrict__ Bm, float* __restrict__ C,
    int M, int N, int K,
    const float* __restrict__ bias1, const float* __restrict__ bias2)
{
    __shared__ unsigned short As[3][128][40];
    __shared__ unsigned short Bs[3][128][40];
    const int bm = blockIdx.y * 128, bn = blockIdx.x * 128;
    const int tid = threadIdx.x;
    const int lane = tid & 63, wid = tid >> 6;
    const int wm = wid >> 1, wn = wid & 1;
    const int lr = lane & 15, lk = (lane >> 4) * 8;

    f32x4 acc[4][4] = {};

    for (int k0 = 0; k0 < K; k0 += 32) {
        #pragma unroll
        for (int p = 0; p < 4; ++p) {
            int flat = p * 256 + tid;
            int c4 = flat & 7, r = flat >> 3;
            float4 v = *(const float4*)&A[(size_t)(bm + r) * K + k0 + c4 * 4];
            unsigned short h[4], l[4], q[4];
            split3(v.x, h[0], l[0], q[0]); split3(v.y, h[1], l[1], q[1]);
            split3(v.z, h[2], l[2], q[2]); split3(v.w, h[3], l[3], q[3]);
            unsigned* dh = (unsigned*)&As[0][r][c4 * 4];
            dh[0] = h[0] | ((unsigned)h[1] << 16); dh[1] = h[2] | ((unsigned)h[3] << 16);
            unsigned* dl = (unsigned*)&As[1][r][c4 * 4];
            dl[0] = l[0] | ((unsigned)l[1] << 16); dl[1] = l[2] | ((unsigned)l[3] << 16);
            unsigned* dq = (unsigned*)&As[2][r][c4 * 4];
            dq[0] = q[0] | ((unsigned)q[1] << 16); dq[1] = q[2] | ((unsigned)q[3] << 16);
        }
        if (BNK) {
            #pragma unroll
            for (int p = 0; p < 4; ++p) {
                int flat = p * 256 + tid;
                int c4 = flat & 7, r = flat >> 3;
                float4 v = *(const float4*)&Bm[(size_t)(bn + r) * K + k0 + c4 * 4];
                unsigned short h[4], l[4], q[4];
                split3(v.x, h[0], l[0], q[0]); split3(v.y, h[1], l[1], q[1]);
                split3(v.z, h[2], l[2], q[2]); split3(v.w, h[3], l[3], q[3]);
                unsigned* dh = (unsigned*)&Bs[0][r][c4 * 4];
                dh[0] = h[0] | ((unsigned)h[1] << 16); dh[1] = h[2] | ((unsigned)h[3] << 16);
                unsigned* dl = (unsigned*)&Bs[1][r][c4 * 4];
                dl[0] = l[0] | ((unsigned)l[1] << 16); dl[1] = l[2] | ((unsigned)l[3] << 16);
                unsigned* dq = (unsigned*)&Bs[2][r][c4 * 4];
                dq[0] = q[0] | ((unsigned)q[1] << 16); dq[1] = q[2] | ((unsigned)q[3] << 16);
            }
        } else {
            #pragma unroll
            for (int p = 0; p < 4; ++p) {
                int flat = p * 256 + tid;
                int n4 = flat & 31, kr = flat >> 5;
                float4 v = *(const float4*)&Bm[(size_t)(k0 + kr) * N + bn + n4 * 4];
                float vv[4] = {v.x, v.y, v.z, v.w};
                #pragma unroll
                for (int jj = 0; jj < 4; ++jj) {
                    unsigned short h, l, q; split3(vv[jj], h, l, q);
                    Bs[0][n4 * 4 + jj][kr] = h;
                    Bs[1][n4 * 4 + jj][kr] = l;
                    Bs[2][n4 * 4 + jj][kr] = q;
                }
            }
        }
        __syncthreads();

        bf16x8 af[3][4], bf[3][4];
        #pragma unroll
        for (int pl = 0; pl < 3; ++pl)
            #pragma unroll
            for (int m = 0; m < 4; ++m) {
                af[pl][m] = *(const bf16x8*)&As[pl][wm * 64 + m * 16 + lr][lk];
                bf[pl][m] = *(const bf16x8*)&Bs[pl][wn * 64 + m * 16 + lr][lk];
            }
        #pragma unroll
        for (int m = 0; m < 4; ++m)
            #pragma unroll
            for (int n = 0; n < 4; ++n) {
                acc[m][n] = __builtin_amdgcn_mfma_f32_16x16x32_bf16(af[0][m], bf[0][n], acc[m][n], 0, 0, 0);
                acc[m][n] = __builtin_amdgcn_mfma_f32_16x16x32_bf16(af[0][m], bf[1][n], acc[m][n], 0, 0, 0);
                acc[m][n] = __builtin_amdgcn_mfma_f32_16x16x32_bf16(af[1][m], bf[0][n], acc[m][n], 0, 0, 0);
                acc[m][n] = __builtin_amdgcn_mfma_f32_16x16x32_bf16(af[1][m], bf[1][n], acc[m][n], 0, 0, 0);
                acc[m][n] = __builtin_amdgcn_mfma_f32_16x16x32_bf16(af[0][m], bf[2][n], acc[m][n], 0, 0, 0);
                acc[m][n] = __builtin_amdgcn_mfma_f32_16x16x32_bf16(af[2][m], bf[0][n], acc[m][n], 0, 0, 0);
            }
        __syncthreads();
    }

    float bv[4];
    #pragma unroll
    for (int n = 0; n < 4; ++n) {
        int col = bn + wn * 64 + n * 16 + lr;
        float x = 0.f;
        if (bias1) x += bias1[col];
        if (bias2) x += bias2[col];
        bv[n] = x;
    }
    #pragma unroll
    for (int m = 0; m < 4; ++m) {
        int rbase = bm + wm * 64 + m * 16 + (lane >> 4) * 4;
        #pragma unroll
        for (int n = 0; n < 4; ++n) {
            int col = bn + wn * 64 + n * 16 + lr;
            #pragma unroll
            for (int r = 0; r < 4; ++r)
                C[(size_t)(rbase + r) * N + col] = acc[m][n][r] + bv[n];
        }
    }
}

// ---------------------------------------------------------------------------
// X GEMM (layer 0 only): Xr[t][col][b] = seq(8192,512) @ W_ih0^T + b0
// ---------------------------------------------------------------------------
__global__ __launch_bounds__(256) void xgemm_kernel(
    const float* __restrict__ A, const unsigned short* __restrict__ Bpl,
    const float* __restrict__ bias1, const float* __restrict__ bias2,
    float* __restrict__ Xr)
{
    __shared__ unsigned short As[3][128][40];
    __shared__ unsigned short Bs[3][128][40];
    const int bm = blockIdx.y * 128, bn = blockIdx.x * 128;
    const int tid = threadIdx.x;
    const int lane = tid & 63, wid = tid >> 6;
    const int wm = wid >> 1, wn = wid & 1;
    const int lr = lane & 15, lg = lane >> 4, lk = lg * 8;

    f32x4 acc[4][4] = {};

    for (int k0 = 0; k0 < E_; k0 += 32) {
        #pragma unroll
        for (int p = 0; p < 4; ++p) {
            int flat = p * 256 + tid;
            int c4 = flat & 7, r = flat >> 3;
            float4 v = *(const float4*)&A[(size_t)(bm + r) * E_ + k0 + c4 * 4];
            unsigned short h[4], l[4], q[4];
            split3(v.x, h[0], l[0], q[0]); split3(v.y, h[1], l[1], q[1]);
            split3(v.z, h[2], l[2], q[2]); split3(v.w, h[3], l[3], q[3]);
            unsigned* dh = (unsigned*)&As[0][r][c4 * 4];
            dh[0] = h[0] | ((unsigned)h[1] << 16); dh[1] = h[2] | ((unsigned)h[3] << 16);
            unsigned* dl = (unsigned*)&As[1][r][c4 * 4];
            dl[0] = l[0] | ((unsigned)l[1] << 16); dl[1] = l[2] | ((unsigned)l[3] << 16);
            unsigned* dq = (unsigned*)&As[2][r][c4 * 4];
            dq[0] = q[0] | ((unsigned)q[1] << 16); dq[1] = q[2] | ((unsigned)q[3] << 16);
        }
        #pragma unroll
        for (int p6 = 0; p6 < 6; ++p6) {
            int f = p6 * 256 + tid;
            int pl = f >> 9, rem = f & 511;
            int r = rem >> 2, g4 = rem & 3;
            const unsigned short* src = Bpl + (size_t)pl * (G4_ * E_) + (size_t)(bn + r) * E_ + k0 + g4 * 8;
            *(uint4*)&Bs[pl][r][g4 * 8] = *(const uint4*)src;
        }
        __syncthreads();

        bf16x8 af[3][4], bf[3][4];
        #pragma unroll
        for (int pl = 0; pl < 3; ++pl)
            #pragma unroll
            for (int m = 0; m < 4; ++m) {
                af[pl][m] = *(const bf16x8*)&As[pl][wm * 64 + m * 16 + lr][lk];
                bf[pl][m] = *(const bf16x8*)&Bs[pl][wn * 64 + m * 16 + lr][lk];
            }
        #pragma unroll
        for (int m = 0; m < 4; ++m)
            #pragma unroll
            for (int n = 0; n < 4; ++n) {
                acc[m][n] = __builtin_amdgcn_mfma_f32_16x16x32_bf16(af[0][m], bf[0][n], acc[m][n], 0, 0, 0);
                acc[m][n] = __builtin_amdgcn_mfma_f32_16x16x32_bf16(af[0][m], bf[1][n], acc[m][n], 0, 0, 0);
                acc[m][n] = __builtin_amdgcn_mfma_f32_16x16x32_bf16(af[1][m], bf[0][n], acc[m][n], 0, 0, 0);
                acc[m][n] = __builtin_amdgcn_mfma_f32_16x16x32_bf16(af[1][m], bf[1][n], acc[m][n], 0, 0, 0);
                acc[m][n] = __builtin_amdgcn_mfma_f32_16x16x32_bf16(af[0][m], bf[2][n], acc[m][n], 0, 0, 0);
                acc[m][n] = __builtin_amdgcn_mfma_f32_16x16x32_bf16(af[2][m], bf[0][n], acc[m][n], 0, 0, 0);
            }
        __syncthreads();
    }

    #pragma unroll
    for (int n = 0; n < 4; ++n) {
        int col = bn + wn * 64 + n * 16 + lr;
        float bv = bias1[col] + bias2[col];
        #pragma unroll
        for (int m = 0; m < 4; ++m) {
            int rbase = bm + wm * 64 + m * 16 + lg * 4;
            #pragma unroll
            for (int r = 0; r < 4; ++r) {
                int row = rbase + r;
                Xr[((size_t)(row >> 6) * G4_ + col) * 64 + (row & 63)] = acc[m][n][r] + bv;
            }
        }
    }
}

// ---------------------------------------------------------------------------
// Fused 2-layer pipelined LSTM recurrence: 256 blocks x 512 threads, 129 ticks.
// Blocks 0-127: layer 0 (R10 k-split: 2 k-halves x 4 bq).
// Blocks 128-255: layer 1 lagged 1 tick:
//   gates1 = u0(t)@Wx1^T + u1(t-1)@Whhr1^T + b1   (Wx1 = W_ih1@W_hr0).
// R13: L1 waves = mat(2) x k-half(2) x bq-pair(2); each wave covers 2 batch
// quadrants over 16 serial ks (chain halved vs R12). Partials combined via
// 3-source psum in LDS; root waves (mat0,kh0) hold c and do elementwise.
// 5-product split (hh,hl,lh,ll,hq) — weight q-planes never streamed.
// Barrier/coherence: R10-proven (sc0sc1 write-through u stores + vmcnt drain;
// relaxed direct-poll barrier, 32 counters x 8 blocks, monotone targets).
// ---------------------------------------------------------------------------
__global__ __launch_bounds__(512, 1) void persistent_lstm(
    const float* __restrict__ Xr,               // [128][4096][64]
    const unsigned short* __restrict__ Wpl0,    // [3][4096*1024] layer0 Whhr
    const unsigned short* __restrict__ WplX,    // [3][4096*1024] Wx1
    const unsigned short* __restrict__ Wpl1,    // [3][4096*1024] layer1 Whhr
    unsigned short* __restrict__ u0r,           // [2][SLOT] ring
    unsigned short* __restrict__ u1ps,          // [129][SLOT]
    const float* __restrict__ bih1,
    const float* __restrict__ bhh1,
    unsigned int* bar)                          // 32 counters, 64B apart
{
    extern __shared__ unsigned short smem[];
    unsigned short* Wlds = smem;                // 131072 B
    unsigned short* u_sm = smem + 65536;        // 3072 B
    float* psum = (float*)(smem + 67072);       // L0: 8KB used; L1: 24KB

    const int tid = threadIdx.x;
    const int j = blockIdx.x;                   // 0..255
    const int wid = tid >> 6, lane = tid & 63;
    const int grp = wid >> 2, bq = wid & 3;     // L0 roles: k-half x bq
    const int mat = wid >> 2, kh = (wid >> 1) & 1, bqp = wid & 1;  // L1 roles
    const int lr = lane & 15, lg = lane >> 4;
    const bool isL0 = (j < 128);
    const int jj = isL0 ? j : (j - 128);
    const int b = bq * 16 + lr;                 // L0 batch index
    const int uoff = b * 8;
    const int bqa = bqp * 2, bqb = bqa + 1;     // L1 batch quadrants
    const int ba = bqa * 16 + lr, bb_ = bqb * 16 + lr;
    const int uoffa = ba * 8, uoffb = bb_ * 8;
    const int swzb = lr & 7;
    const int gr0 = (lr & 3) * 1024 + jj * 8 + (lr >> 2);
    const int gr1 = gr0 + 4;

    float c0 = 0.f, c1 = 0.f, c2 = 0.f, c3 = 0.f;  // L1 root: tiles x 2 bq
    float b1v0[4], b1v1[4];

    if (isL0) {
        // stage hi/lo planes of Whhr0's 32 gate-rows (R10-exact)
        for (int it = 0; it < 16; ++it) {
            int f = it * 512 + tid;
            int p = f >> 12;
            int rem = f & 4095;
            int h2 = rem >> 11;
            int rem2 = rem & 2047;
            int n = rem2 >> 7;
            int g16 = rem2 & 127;
            int gr = (n & 3) * 1024 + jj * 8 + h2 * 4 + (n >> 2);
            const unsigned short* src = Wpl0 + (size_t)p * (G4_ * H_) + (size_t)gr * H_ + g16 * 8;
            *(uint4*)&Wlds[(size_t)((p * 2 + h2) * 16 + n) * 1024 + (g16 ^ (n & 7)) * 8] = *(const uint4*)src;
        }
    } else {
        // stage hi planes of BOTH matrices (Wx1, Whhr1): [mat][h2][16][1024]
        for (int it = 0; it < 16; ++it) {
            int f = it * 512 + tid;
            int m = f >> 12;
            int rem = f & 4095;
            int h2 = rem >> 11;
            int rem2 = rem & 2047;
            int n = rem2 >> 7;
            int g16 = rem2 & 127;
            int gr = (n & 3) * 1024 + jj * 8 + h2 * 4 + (n >> 2);
            const unsigned short* base = (m == 0) ? WplX : Wpl1;
            const unsigned short* src = base + (size_t)gr * H_ + g16 * 8;   // plane 0 = hi
            *(uint4*)&Wlds[(size_t)((m * 2 + h2) * 16 + n) * 1024 + (g16 ^ (n & 7)) * 8] = *(const uint4*)src;
        }
        #pragma unroll
        for (int g = 0; g < 4; ++g) {
            int idx = g * 1024 + jj * 8 + lg;
            b1v0[g] = bih1[idx] + bhh1[idx];
            b1v1[g] = bih1[idx + 4] + bhh1[idx + 4];
        }
    }
    __syncthreads();

    // L1 streamed lo rows of this wave's matrix (plane 1)
    const unsigned short* mbase = (mat == 0) ? WplX : Wpl1;
    const unsigned short* ml0 = mbase + (size_t)1 * (G4_ * H_) + (size_t)gr0 * H_;
    const unsigned short* ml1 = mbase + (size_t)1 * (G4_ * H_) + (size_t)gr1 * H_;

    for (int tau = 0; tau <= T_; ++tau) {
        if (isL0) {
            if (tau < T_) {
                const int t = tau;
                const unsigned short* ut = u0r + (size_t)(t & 1) * SLOT;
                float xg0[4], xg1[4];
                if (grp == 0) {
                    #pragma unroll
                    for (int g = 0; g < 4; ++g) {
                        xg0[g] = Xr[((size_t)t * G4_ + g * 1024 + jj * 8 + lg) * 64 + b];
                        xg1[g] = Xr[((size_t)t * G4_ + g * 1024 + jj * 8 + 4 + lg) * 64 + b];
                    }
                }
                f32x4 a0 = {0.f,0.f,0.f,0.f}, p0 = {0.f,0.f,0.f,0.f};
                f32x4 a1 = {0.f,0.f,0.f,0.f}, p1 = {0.f,0.f,0.f,0.f};
                const int kbase = grp * 64;
                #pragma unroll 8
                for (int ks = 0; ks < 16; ++ks) {
                    int g16 = kbase + ks * 4 + lg;
                    int swz = (g16 ^ swzb) * 8;
                    bf16x8 uh = *(const bf16x8*)&ut[(size_t)g16 * 512 + uoff];
                    bf16x8 ul = *(const bf16x8*)&ut[PSTR + (size_t)g16 * 512 + uoff];
                    bf16x8 uq = *(const bf16x8*)&ut[2 * PSTR + (size_t)g16 * 512 + uoff];
                    bf16x8 wh0 = *(const bf16x8*)&Wlds[(size_t)(0 * 16 + lr) * 1024 + swz];
                    bf16x8 wh1 = *(const bf16x8*)&Wlds[(size_t)(1 * 16 + lr) * 1024 + swz];
                    bf16x8 wl0 = *(const bf16x8*)&Wlds[(size_t)(2 * 16 + lr) * 1024 + swz];
                    bf16x8 wl1 = *(const bf16x8*)&Wlds[(size_t)(3 * 16 + lr) * 1024 + swz];
                    a0 = __builtin_amdgcn_mfma_f32_16x16x32_bf16(wh0, uh, a0, 0, 0, 0);
                    a0 = __builtin_amdgcn_mfma_f32_16x16x32_bf16(wh0, ul, a0, 0, 0, 0);
                    a0 = __builtin_amdgcn_mfma_f32_16x16x32_bf16(wl0, uh, a0, 0, 0, 0);
                    p0 = __builtin_amdgcn_mfma_f32_16x16x32_bf16(wl0, ul, p0, 0, 0, 0);
                    p0 = __builtin_amdgcn_mfma_f32_16x16x32_bf16(wh0, uq, p0, 0, 0, 0);
                    a1 = __builtin_amdgcn_mfma_f32_16x16x32_bf16(wh1, uh, a1, 0, 0, 0);
                    a1 = __builtin_amdgcn_mfma_f32_16x16x32_bf16(wh1, ul, a1, 0, 0, 0);
                    a1 = __builtin_amdgcn_mfma_f32_16x16x32_bf16(wl1, uh, a1, 0, 0, 0);
                    p1 = __builtin_amdgcn_mfma_f32_16x16x32_bf16(wl1, ul, p1, 0, 0, 0);
                    p1 = __builtin_amdgcn_mfma_f32_16x16x32_bf16(wh1, uq, p1, 0, 0, 0);
                }
                if (grp == 1) {
                    float* pp = &psum[(size_t)(bq * 64 + lane) * 8];
                    *(f32x4*)&pp[0] = a0 + p0;
                    *(f32x4*)&pp[4] = a1 + p1;
                }
                __syncthreads();
                if (grp == 0) {
                    const float* pp = &psum[(size_t)(bq * 64 + lane) * 8];
                    f32x4 s0o = *(const f32x4*)&pp[0];
                    f32x4 s1o = *(const f32x4*)&pp[4];
                    {
                        float gi = a0[0]+p0[0]+s0o[0]+xg0[0];
                        float gf = a0[1]+p0[1]+s0o[1]+xg0[1];
                        float gv = a0[2]+p0[2]+s0o[2]+xg0[2];
                        float go = a0[3]+p0[3]+s0o[3]+xg0[3];
                        float si = 1.f/(1.f+__expf(-gi));
                        float sf = 1.f/(1.f+__expf(-gf));
                        float so = 1.f/(1.f+__expf(-go));
                        c0 = sf*c0 + si*tanhf(gv);
                        float ho = so*tanhf(c0);
                        unsigned short sh, sl, sq; split3(ho, sh, sl, sq);
                        u_sm[(0*64+b)*8+lg] = sh; u_sm[(1*64+b)*8+lg] = sl; u_sm[(2*64+b)*8+lg] = sq;
                    }
                    {
                        float gi = a1[0]+p1[0]+s1o[0]+xg1[0];
                        float gf = a1[1]+p1[1]+s1o[1]+xg1[1];
                        float gv = a1[2]+p1[2]+s1o[2]+xg1[2];
                        float go = a1[3]+p1[3]+s1o[3]+xg1[3];
                        float si = 1.f/(1.f+__expf(-gi));
                        float sf = 1.f/(1.f+__expf(-gf));
                        float so = 1.f/(1.f+__expf(-go));
                        c1 = sf*c1 + si*tanhf(gv);
                        float ho = so*tanhf(c1);
                        unsigned short sh, sl, sq; split3(ho, sh, sl, sq);
                        u_sm[(0*64+b)*8+4+lg] = sh; u_sm[(1*64+b)*8+4+lg] = sl; u_sm[(2*64+b)*8+4+lg] = sq;
                    }
                }
                __syncthreads();
                if (tid < 192) {
                    int pl = tid >> 6, bb = tid & 63;
                    u32x4 v = *(const u32x4*)&u_sm[(pl * 64 + bb) * 8];
                    unsigned short* dst = u0r + (size_t)((t + 1) & 1) * SLOT
                                        + (size_t)pl * PSTR + (size_t)(jj * 64 + bb) * 8;
                    asm volatile("global_store_dwordx4 %0, %1, off sc0 sc1"
                                 :: "v"(dst), "v"(v) : "memory");
                }
            }
        } else {
            if (tau >= 1) {
                const int t = tau;
                const unsigned short* u0b = u0r + (size_t)(t & 1) * SLOT;      // u0(t)
                const unsigned short* u1b = u1ps + (size_t)(t - 1) * SLOT;     // u1(t-1)
                const unsigned short* ub = (mat == 0) ? u0b : u1b;
                f32x4 a0a = {0.f,0.f,0.f,0.f}, p0a = {0.f,0.f,0.f,0.f};
                f32x4 a1a = {0.f,0.f,0.f,0.f}, p1a = {0.f,0.f,0.f,0.f};
                f32x4 a0b = {0.f,0.f,0.f,0.f}, p0b = {0.f,0.f,0.f,0.f};
                f32x4 a1b = {0.f,0.f,0.f,0.f}, p1b = {0.f,0.f,0.f,0.f};
                const int lbase = mat * 32;
                #pragma unroll 8
                for (int ks = 0; ks < 16; ++ks) {
                    int g16 = kh * 64 + ks * 4 + lg;
                    int swz = (g16 ^ swzb) * 8;
                    bf16x8 uha = *(const bf16x8*)&ub[(size_t)g16 * 512 + uoffa];
                    bf16x8 ula = *(const bf16x8*)&ub[PSTR + (size_t)g16 * 512 + uoffa];
                    bf16x8 uqa = *(const bf16x8*)&ub[2 * PSTR + (size_t)g16 * 512 + uoffa];
                    bf16x8 uhb = *(const bf16x8*)&ub[(size_t)g16 * 512 + uoffb];
                    bf16x8 ulb = *(const bf16x8*)&ub[PSTR + (size_t)g16 * 512 + uoffb];
                    bf16x8 uqb = *(const bf16x8*)&ub[2 * PSTR + (size_t)g16 * 512 + uoffb];
                    bf16x8 wh0 = *(const bf16x8*)&Wlds[(size_t)(lbase + lr) * 1024 + swz];
                    bf16x8 wh1 = *(const bf16x8*)&Wlds[(size_t)(lbase + 16 + lr) * 1024 + swz];
                    bf16x8 wl0v = *(const bf16x8*)&ml0[g16 * 8];
                    bf16x8 wl1v = *(const bf16x8*)&ml1[g16 * 8];
                    a0a = __builtin_amdgcn_mfma_f32_16x16x32_bf16(wh0, uha, a0a, 0, 0, 0);
                    a0a = __builtin_amdgcn_mfma_f32_16x16x32_bf16(wh0, ula, a0a, 0, 0, 0);
                    a0a = __builtin_amdgcn_mfma_f32_16x16x32_bf16(wl0v, uha, a0a, 0, 0, 0);
                    p0a = __builtin_amdgcn_mfma_f32_16x16x32_bf16(wl0v, ula, p0a, 0, 0, 0);
                    p0a = __builtin_amdgcn_mfma_f32_16x16x32_bf16(wh0, uqa, p0a, 0, 0, 0);
                    a1a = __builtin_amdgcn_mfma_f32_16x16x32_bf16(wh1, uha, a1a, 0, 0, 0);
                    a1a = __builtin_amdgcn_mfma_f32_16x16x32_bf16(wh1, ula, a1a, 0, 0, 0);
                    a1a = __builtin_amdgcn_mfma_f32_16x16x32_bf16(wl1v, uha, a1a, 0, 0, 0);
                    p1a = __builtin_amdgcn_mfma_f32_16x16x32_bf16(wl1v, ula, p1a, 0, 0, 0);
                    p1a = __builtin_amdgcn_mfma_f32_16x16x32_bf16(wh1, uqa, p1a, 0, 0, 0);
                    a0b = __builtin_amdgcn_mfma_f32_16x16x32_bf16(wh0, uhb, a0b, 0, 0, 0);
                    a0b = __builtin_amdgcn_mfma_f32_16x16x32_bf16(wh0, ulb, a0b, 0, 0, 0);
                    a0b = __builtin_amdgcn_mfma_f32_16x16x32_bf16(wl0v, uhb, a0b, 0, 0, 0);
                    p0b = __builtin_amdgcn_mfma_f32_16x16x32_bf16(wl0v, ulb, p0b, 0, 0, 0);
                    p0b = __builtin_amdgcn_mfma_f32_16x16x32_bf16(wh0, uqb, p0b, 0, 0, 0);
                    a1b = __builtin_amdgcn_mfma_f32_16x16x32_bf16(wh1, uhb, a1b, 0, 0, 0);
                    a1b = __builtin_amdgcn_mfma_f32_16x16x32_bf16(wh1, ulb, a1b, 0, 0, 0);
                    a1b = __builtin_amdgcn_mfma_f32_16x16x32_bf16(wl1v, uhb, a1b, 0, 0, 0);
                    p1b = __builtin_amdgcn_mfma_f32_16x16x32_bf16(wl1v, ulb, p1b, 0, 0, 0);
                    p1b = __builtin_amdgcn_mfma_f32_16x16x32_bf16(wh1, uqb, p1b, 0, 0, 0);
                }
                const int src = mat * 2 + kh;
                if (src != 0) {
                    float* ppa = &psum[(size_t)(((src - 1) * 4 + bqa) * 64 + lane) * 8];
                    *(f32x4*)&ppa[0] = a0a + p0a;
                    *(f32x4*)&ppa[4] = a1a + p1a;
                    float* ppb = &psum[(size_t)(((src - 1) * 4 + bqb) * 64 + lane) * 8];
                    *(f32x4*)&ppb[0] = a0b + p0b;
                    *(f32x4*)&ppb[4] = a1b + p1b;
                }
                __syncthreads();
                if (src == 0) {
                    #pragma unroll
                    for (int half = 0; half < 2; ++half) {
                        const int bqx = half ? bqb : bqa;
                        const int bx = bqx * 16 + lr;
                        f32x4 s0 = half ? (a0b + p0b) : (a0a + p0a);
                        f32x4 s1 = half ? (a1b + p1b) : (a1a + p1a);
                        #pragma unroll
                        for (int s = 0; s < 3; ++s) {
                            const float* pp = &psum[(size_t)((s * 4 + bqx) * 64 + lane) * 8];
                            s0 += *(const f32x4*)&pp[0];
                            s1 += *(const f32x4*)&pp[4];
                        }
                        float& cA = half ? c2 : c0;
                        float& cB = half ? c3 : c1;
                        {
                            float gi = s0[0]+b1v0[0], gf = s0[1]+b1v0[1];
                            float gv = s0[2]+b1v0[2], go = s0[3]+b1v0[3];
                            float si = 1.f/(1.f+__expf(-gi));
                            float sf = 1.f/(1.f+__expf(-gf));
                            float so = 1.f/(1.f+__expf(-go));
                            cA = sf*cA + si*tanhf(gv);
                            float ho = so*tanhf(cA);
                            unsigned short sh, sl, sq; split3(ho, sh, sl, sq);
                            u_sm[(0*64+bx)*8+lg] = sh; u_sm[(1*64+bx)*8+lg] = sl; u_sm[(2*64+bx)*8+lg] = sq;
                        }
                        {
                            float gi = s1[0]+b1v1[0], gf = s1[1]+b1v1[1];
                            float gv = s1[2]+b1v1[2], go = s1[3]+b1v1[3];
                            float si = 1.f/(1.f+__expf(-gi));
                            float sf = 1.f/(1.f+__expf(-gf));
                            float so = 1.f/(1.f+__expf(-go));
                            cB = sf*cB + si*tanhf(gv);
                            float ho = so*tanhf(cB);
                            unsigned short sh, sl, sq; split3(ho, sh, sl, sq);
                            u_sm[(0*64+bx)*8+4+lg] = sh; u_sm[(1*64+bx)*8+4+lg] = sl; u_sm[(2*64+bx)*8+4+lg] = sq;
                        }
                    }
                }
                __syncthreads();
                if (tid < 192) {
                    int pl = tid >> 6, bb = tid & 63;
                    u32x4 v = *(const u32x4*)&u_sm[(pl * 64 + bb) * 8];
                    unsigned short* dst = u1ps + (size_t)t * SLOT
                                        + (size_t)pl * PSTR + (size_t)(jj * 64 + bb) * 8;
                    asm volatile("global_store_dwordx4 %0, %1, off sc0 sc1"
                                 :: "v"(dst), "v"(v) : "memory");
                }
            }
        }

        if (tau < T_) {
            asm volatile("s_waitcnt vmcnt(0)" ::: "memory");
            __syncthreads();
            if (tid == 0)
                __hip_atomic_fetch_add(&bar[(j & 31) * 16], 1u,
                                       __ATOMIC_RELAXED, __HIP_MEMORY_SCOPE_AGENT);
            if (tid < 32) {
                const unsigned tgt = (unsigned)(tau + 1) * 8u;
                while (__hip_atomic_load(&bar[tid * 16],
                                         __ATOMIC_RELAXED, __HIP_MEMORY_SCOPE_AGENT) < tgt) {}
            }
            __syncthreads();
        }
    }
}

// ---------------------------------------------------------------------------
// Projection GEMM: logits(8192,512) = U1(8192,1024) @ W_hr1^T
// ---------------------------------------------------------------------------
__global__ __launch_bounds__(256) void proj_gemm(
    const unsigned short* __restrict__ u_ps,   // [129][SLOT]
    const float* __restrict__ Whr,             // (512,1024) f32 (N,K)
    float* __restrict__ C)                     // (8192,512)
{
    __shared__ unsigned short Bs[3][128][40];
    const int bn = blockIdx.x * 128;
    const int bm = blockIdx.y * 128;
    const int tid = threadIdx.x;
    const int lane = tid & 63, wid = tid >> 6;
    const int wm = wid >> 1, wn = wid & 1;
    const int lr = lane & 15, lg = lane >> 4, lk = lg * 8;

    f32x4 acc[4][4] = {};
    const int t = (bm >> 6) + wm;
    const unsigned short* ut = u_ps + (size_t)(t + 1) * SLOT;

    for (int k0 = 0; k0 < H_; k0 += 32) {
        #pragma unroll
        for (int p = 0; p < 4; ++p) {
            int flat = p * 256 + tid;
            int c4 = flat & 7, r = flat >> 3;
            float4 v = *(const float4*)&Whr[(size_t)(bn + r) * H_ + k0 + c4 * 4];
            unsigned short h[4], l[4], q[4];
            split3(v.x, h[0], l[0], q[0]); split3(v.y, h[1], l[1], q[1]);
            split3(v.z, h[2], l[2], q[2]); split3(v.w, h[3], l[3], q[3]);
            unsigned* dh = (unsigned*)&Bs[0][r][c4 * 4];
            dh[0] = h[0] | ((unsigned)h[1] << 16); dh[1] = h[2] | ((unsigned)h[3] << 16);
            unsigned* dl = (unsigned*)&Bs[1][r][c4 * 4];
            dl[0] = l[0] | ((unsigned)l[1] << 16); dl[1] = l[2] | ((unsigned)l[3] << 16);
            unsigned* dq = (unsigned*)&Bs[2][r][c4 * 4];
            dq[0] = q[0] | ((unsigned)q[1] << 16); dq[1] = q[2] | ((unsigned)q[3] << 16);
        }
        __syncthreads();

        int ks = k0 >> 5;
        bf16x8 af[3][4], bf[3][4];
        #pragma unroll
        for (int pl = 0; pl < 3; ++pl)
            #pragma unroll
            for (int m = 0; m < 4; ++m) {
                af[pl][m] = *(const bf16x8*)&ut[(size_t)pl * PSTR + (size_t)((ks * 4 + lg) * 64 + m * 16 + lr) * 8];
                bf[pl][m] = *(const bf16x8*)&Bs[pl][wn * 64 + m * 16 + lr][lk];
            }
        #pragma unroll
        for (int m = 0; m < 4; ++m)
            #pragma unroll
            for (int n = 0; n < 4; ++n) {
                acc[m][n] = __builtin_amdgcn_mfma_f32_16x16x32_bf16(af[0][m], bf[0][n], acc[m][n], 0, 0, 0);
                acc[m][n] = __builtin_amdgcn_mfma_f32_16x16x32_bf16(af[0][m], bf[1][n], acc[m][n], 0, 0, 0);
                acc[m][n] = __builtin_amdgcn_mfma_f32_16x16x32_bf16(af[1][m], bf[0][n], acc[m][n], 0, 0, 0);
                acc[m][n] = __builtin_amdgcn_mfma_f32_16x16x32_bf16(af[1][m], bf[1][n], acc[m][n], 0, 0, 0);
                acc[m][n] = __builtin_amdgcn_mfma_f32_16x16x32_bf16(af[0][m], bf[2][n], acc[m][n], 0, 0, 0);
                acc[m][n] = __builtin_amdgcn_mfma_f32_16x16x32_bf16(af[2][m], bf[0][n], acc[m][n], 0, 0, 0);
            }
        __syncthreads();
    }

    #pragma unroll
    for (int m = 0; m < 4; ++m) {
        int rbase = bm + wm * 64 + m * 16 + lg * 4;
        #pragma unroll
        for (int n = 0; n < 4; ++n) {
            int col = bn + wn * 64 + n * 16 + lr;
            #pragma unroll
            for (int r = 0; r < 4; ++r)
                C[(size_t)(rbase + r) * E_ + col] = acc[m][n][r];
        }
    }
}

// ---------------------------------------------------------------------------
// Row softmax over E=512; input rows m = t*64+b, output row (b, t).
// ---------------------------------------------------------------------------
__global__ __launch_bounds__(256) void softmax_kernel(
    const float* __restrict__ LOG, float* __restrict__ out)
{
    const int lane = threadIdx.x & 63;
    const int r = blockIdx.x * 4 + (threadIdx.x >> 6);
    const float* src = LOG + (size_t)r * E_;
    float v[8];
    *(float4*)&v[0] = ((const float4*)src)[lane * 2];
    *(float4*)&v[4] = ((const float4*)src)[lane * 2 + 1];

    float m = v[0];
    #pragma unroll
    for (int i = 1; i < 8; ++i) m = fmaxf(m, v[i]);
    #pragma unroll
    for (int off = 32; off > 0; off >>= 1) m = fmaxf(m, __shfl_xor(m, off, 64));

    float s = 0.f;
    #pragma unroll
    for (int i = 0; i < 8; ++i) { v[i] = expf(v[i] - m); s += v[i]; }
    #pragma unroll
    for (int off = 32; off > 0; off >>= 1) s += __shfl_xor(s, off, 64);
    const float inv = 1.f / s;

    const int t = r >> 6, b = r & 63;
    float* dst = out + ((size_t)b * T_ + t) * E_;
    #pragma unroll
    for (int i = 0; i < 8; ++i) v[i] *= inv;
    ((float4*)dst)[lane * 2]     = *(float4*)&v[0];
    ((float4*)dst)[lane * 2 + 1] = *(float4*)&v[4];
}

// ---------------------------------------------------------------------------
extern "C" void kernel_launch(void* const* d_in, const int* in_sizes, int n_in,
                              void* d_out, int out_size, void* d_ws, size_t ws_size,
                              hipStream_t stream)
{
    const float* images   = (const float*)d_in[0];
    const int*   captions = (const int*)  d_in[1];
    const float* table    = (const float*)d_in[2];
    const float* W_ih     = (const float*)d_in[3];
    const float* W_hh     = (const float*)d_in[4];
    const float* W_hr     = (const float*)d_in[5];
    const float* b_ih     = (const float*)d_in[6];
    const float* b_hh     = (const float*)d_in[7];
    float* out = (float*)d_out;

    // Workspace layout (byte offsets)
    char* base = (char*)d_ws;
    float*          Xr    = (float*)base;                            // 134,217,728
    unsigned int*   bar   = (unsigned int*)(base + 134217728);       //       4,096
    unsigned short* u0r   = (unsigned short*)(base + 134221824);     //     786,432 (2 slots)
    unsigned short* u1ps  = (unsigned short*)(base + 135008256);     //  50,724,864 (129 slots)
    unsigned short* Wpl0  = (unsigned short*)(base + 185733120);     //  25,165,824
    unsigned short* Wpl1  = (unsigned short*)(base + 210898944);     //  25,165,824
    unsigned short* WplX  = (unsigned short*)(base + 236064768);     //  25,165,824
    // sequentially-dead aliases inside u1ps (overwritten later by coop kernel)
    float* WF32 = (float*)((char*)u1ps + 393216);                    // 16.8MB scratch
    float* seq  = (float*)((char*)u1ps + 17170432);                  // 16.8MB
    float* logits = Xr;

    const int SMEM_BYTES = 131072 + 3072 + 24576;
    (void)hipFuncSetAttribute((const void*)persistent_lstm,
                              hipFuncAttributeMaxDynamicSharedMemorySize, SMEM_BYTES);

    const float* wih0 = W_ih;
    const float* wih1 = W_ih + (size_t)G4_ * E_;
    const float* whh0 = W_hh;
    const float* whh1 = W_hh + (size_t)G4_ * E_;
    const float* whr0 = W_hr;
    const float* whr1 = W_hr + (size_t)E_ * H_;

    embed_kernel<<<T_ * B_, 128, 0, stream>>>(images, captions, table, seq);

    // weight products (all f32 via scratch, then 3-plane split)
    mfma_gemm<false><<<dim3(H_ / 128, G4_ / 128), 256, 0, stream>>>(
        whh0, whr0, WF32, G4_, H_, E_, nullptr, nullptr);
    split_planes<<<(G4_ * H_) / 1024, 256, 0, stream>>>(WF32, Wpl0, (size_t)G4_ * H_);

    mfma_gemm<false><<<dim3(H_ / 128, G4_ / 128), 256, 0, stream>>>(
        whh1, whr1, WF32, G4_, H_, E_, nullptr, nullptr);
    split_planes<<<(G4_ * H_) / 1024, 256, 0, stream>>>(WF32, Wpl1, (size_t)G4_ * H_);

    mfma_gemm<false><<<dim3(H_ / 128, G4_ / 128), 256, 0, stream>>>(
        wih1, whr0, WF32, G4_, H_, E_, nullptr, nullptr);
    split_planes<<<(G4_ * H_) / 1024, 256, 0, stream>>>(WF32, WplX, (size_t)G4_ * H_);

    // X0 = seq @ W_ih0^T + b_ih0 + b_hh0, stored [t][col][b]
    {
        unsigned short* WihPl = (unsigned short*)((char*)u1ps + 33947648); // 12.6MB
        split_planes<<<(G4_ * E_) / 1024, 256, 0, stream>>>(wih0, WihPl, (size_t)G4_ * E_);
        xgemm_kernel<<<dim3(G4_ / 128, (T_ * B_) / 128), 256, 0, stream>>>(
            seq, WihPl, b_ih, b_hh, Xr);
    }

    // zero u0(0), u1(0), barrier
    (void)hipMemsetAsync(u0r, 0, SLOT * sizeof(unsigned short), stream);
    (void)hipMemsetAsync(u1ps, 0, SLOT * sizeof(unsigned short), stream);
    (void)hipMemsetAsync(bar, 0, 4096, stream);

    // fused 2-layer pipelined recurrence: one cooperative launch, 129 ticks
    {
        const float* xr_a = Xr;
        const unsigned short* w0_a = Wpl0;
        const unsigned short* wx_a = WplX;
        const unsigned short* w1_a = Wpl1;
        unsigned short* u0_a = u0r;
        unsigned short* u1_a = u1ps;
        const float* bi1_a = b_ih + G4_;
        const float* bh1_a = b_hh + G4_;
        unsigned int* bar_a = bar;
        void* args[] = { (void*)&xr_a, (void*)&w0_a, (void*)&wx_a, (void*)&w1_a,
                         (void*)&u0_a, (void*)&u1_a, (void*)&bi1_a, (void*)&bh1_a,
                         (void*)&bar_a };
        (void)hipLaunchCooperativeKernel((const void*)persistent_lstm,
                                         dim3(256), dim3(512), args, SMEM_BYTES, stream);
    }

    // logits = u1 @ W_hr1^T  -> softmax
    proj_gemm<<<dim3(E_ / 128, (T_ * B_) / 128), 256, 0, stream>>>(u1ps, whr1, logits);
    softmax_kernel<<<(T_ * B_) / 4, 256, 0, stream>>>(logits, out);

    (void)in_sizes; (void)n_in; (void)out_size; (void)ws_size;
}